// Round 2
// baseline (324.211 us; speedup 1.0000x reference)
//
#include <hip/hip_runtime.h>

// Fused GQA attention block: QKV proj(+RoPE, +V-transpose) -> flash attn -> out proj.
// B=2 S=2048 D=2048 H=16 KV=4 HD=128. All MFMA compute in bf16 (tol = 2% of max).

#define B_  2
#define S_  2048
#define D_  2048
#define H_  16
#define KV_ 4
#define HD_ 128
#define NQK 2560    // QK buffer row stride: 2048 (Q) + 512 (K); V goes to Vt directly

typedef unsigned short ushort_t;
typedef __attribute__((ext_vector_type(8))) __bf16 bf16x8;
typedef __attribute__((ext_vector_type(4))) float  f32x4;

__device__ __forceinline__ ushort_t f2bf(float f) {
    unsigned u = __float_as_uint(f);
    u += 0x7FFFu + ((u >> 16) & 1u);          // round-to-nearest-even
    return (ushort_t)(u >> 16);
}
__device__ __forceinline__ float bf2f(ushort_t h) {
    return __uint_as_float(((unsigned)h) << 16);
}

// async global->LDS, 16B per lane; LDS dest = wave-uniform base + lane*16
__device__ __forceinline__ void g2l16(const void* g, void* l) {
    __builtin_amdgcn_global_load_lds(
        (const __attribute__((address_space(1))) unsigned int*)g,
        (__attribute__((address_space(3))) unsigned int*)l, 16, 0, 0);
}

// ---------------- fused prep: x->bf16, 4 weight transposes, bias pack -------

__global__ __launch_bounds__(256) void k_prep(
    const float* __restrict__ x,  ushort_t* __restrict__ xb,
    const float* __restrict__ Wq, const float* __restrict__ Wk,
    const float* __restrict__ Wv, const float* __restrict__ Wo,
    ushort_t* __restrict__ Wt, ushort_t* __restrict__ Wot,
    const float* __restrict__ bq, const float* __restrict__ bk,
    const float* __restrict__ bv, float* __restrict__ bb) {
    __shared__ float tile[32][33];
    int id = blockIdx.x, t = threadIdx.x;
    if (id < 8192) {                                   // x fp32 -> bf16
        int i = id * 256 + t;
        float4 v = ((const float4*)x)[i];
        ushort4 o;
        o.x = f2bf(v.x); o.y = f2bf(v.y); o.z = f2bf(v.z); o.w = f2bf(v.w);
        ((ushort4*)xb)[i] = o;
        return;
    }
    const float* src; ushort_t* dst; int C, bid;
    if (id < 12288)      { src = Wq; dst = Wt;                       C = 2048; bid = id - 8192;  }
    else if (id < 13312) { src = Wk; dst = Wt + (size_t)2048 * 2048; C = 512;  bid = id - 12288; }
    else if (id < 14336) { src = Wv; dst = Wt + (size_t)2560 * 2048; C = 512;  bid = id - 13312; }
    else if (id < 18432) { src = Wo; dst = Wot;                      C = 2048; bid = id - 14336; }
    else {                                             // bias pack
        int i = (id - 18432) * 256 + t;
        if (i < 3072)
            bb[i] = (i < 2048) ? bq[i] : (i < 2560) ? bk[i - 2048] : bv[i - 2560];
        return;
    }
    const int R = 2048;
    int nbc = C >> 5;
    int c0 = (bid % nbc) * 32, r0 = (bid / nbc) * 32;
    int tx = t & 31, ty = t >> 5;
    for (int i = ty; i < 32; i += 8)
        tile[i][tx] = src[(size_t)(r0 + i) * C + c0 + tx];
    __syncthreads();
    for (int i = ty; i < 32; i += 8)
        dst[(size_t)(c0 + i) * R + r0 + tx] = f2bf(tile[tx][i]);
}

// ---------------- gemm2: 128x128 tile, 2-phase (unchanged, out proj only) ---

template<int BK>
__global__ __launch_bounds__(256, 3) void k_gemm(const ushort_t* __restrict__ A,
                                                 const ushort_t* __restrict__ Bt,
                                                 void* __restrict__ Cp,
                                                 const float* __restrict__ bias,
                                                 const float* __restrict__ fc,
                                                 const float* __restrict__ fs,
                                                 ushort_t* __restrict__ Vt,
                                                 int M, int N, int K, int out_bf16) {
    constexpr int GPR    = BK / 8;    // 16B granules per row
    constexpr int RPR    = 64 / GPR;  // rows staged per round per wave
    constexpr int ROUNDS = 32 / RPR;  // rounds to cover 32 rows per wave
    __shared__ __align__(16) ushort_t As[128 * BK];
    __shared__ __align__(16) ushort_t Bs[128 * BK];
    int t = threadIdx.x;
    int w = t >> 6, lane = t & 63, quad = lane >> 4, l16 = lane & 15;
    int L = blockIdx.x;
    int mper = (M >> 7) >> 3;                 // m-tiles per XCD
    int xcd = L & 7, j = L >> 3;
    int m0 = (xcd * mper + (j % mper)) * 128;
    int n0 = (j / mper) * 128;
    int wm = (w >> 1) * 64, wn = (w & 1) * 64;
    f32x4 acc[4][4] = {};

    int rlo = lane / GPR;                     // row-within-round
    int gsl = lane & (GPR - 1);               // slot granule
    const ushort_t* Ag = A  + (size_t)(m0 + w * 32) * K;
    const ushort_t* Bg = Bt + (size_t)(n0 + w * 32) * K;
    int rsw = (l16 & 7);                      // read-side swizzle bits

    for (int k0 = 0; k0 < K; k0 += BK) {
        __syncthreads();
#pragma unroll
        for (int p = 0; p < ROUNDS; p++) {
            int row = p * RPR + rlo;
            int gs = gsl ^ (row & 7);
            g2l16(Ag + (size_t)row * K + k0 + gs * 8, (char*)As + (w * 32 + p * RPR) * 2 * BK);
            g2l16(Bg + (size_t)row * K + k0 + gs * 8, (char*)Bs + (w * 32 + p * RPR) * 2 * BK);
        }
        __syncthreads();
#pragma unroll
        for (int kc = 0; kc < BK / 32; kc++) {
            int gg = quad + kc * 4;
            bf16x8 af[4], bfr[4];
#pragma unroll
            for (int i = 0; i < 4; i++)
                af[i] = *(const bf16x8*)(As + (wm + i * 16 + l16) * BK + ((gg ^ rsw) * 8));
#pragma unroll
            for (int j2 = 0; j2 < 4; j2++)
                bfr[j2] = *(const bf16x8*)(Bs + (wn + j2 * 16 + l16) * BK + ((gg ^ rsw) * 8));
#pragma unroll
            for (int i = 0; i < 4; i++)
#pragma unroll
                for (int j2 = 0; j2 < 4; j2++)
                    acc[i][j2] = __builtin_amdgcn_mfma_f32_16x16x32_bf16(af[i], bfr[j2], acc[i][j2], 0, 0, 0);
        }
    }
    int ostride = fc ? NQK : N;
#pragma unroll
    for (int i = 0; i < 4; i++) {
        int r = m0 + wm + i * 16 + quad * 4;
#pragma unroll
        for (int j2 = 0; j2 < 4; j2++) {
            int c = n0 + wn + j2 * 16 + l16;
            float bv_ = bias ? bias[c] : 0.f;
            if (fc && c >= 2560) {
                ushort4 pack;
                pack.x = f2bf(acc[i][j2][0] + bv_);
                pack.y = f2bf(acc[i][j2][1] + bv_);
                pack.z = f2bf(acc[i][j2][2] + bv_);
                pack.w = f2bf(acc[i][j2][3] + bv_);
                int kv = (c - 2560) >> 7, d = (c - 2560) & 127;
                int b = r >> 11, s0 = r & (S_ - 1);
                *(ushort4*)&Vt[(((size_t)b * KV_ + kv) * HD_ + d) * S_ + s0] = pack;
                continue;
            }
#pragma unroll
            for (int jr = 0; jr < 4; jr++) {
                float v = acc[i][j2][jr] + bv_;
                if (fc) {
                    int s  = (r + jr) & (S_ - 1);
                    int dp = (c & 127) >> 1;
                    float cs = fc[s * 64 + dp], sn = fs[s * 64 + dp];
                    float p = __shfl_xor(v, 1);
                    v = (c & 1) ? (v * cs + p * sn) : (v * cs - p * sn);
                }
                if (out_bf16) ((ushort_t*)Cp)[(size_t)(r + jr) * ostride + c] = f2bf(v);
                else          ((float*)Cp)[(size_t)(r + jr) * ostride + c] = v;
            }
        }
    }
}

// ---------------- gemm1: 256x256 8-phase counted-vmcnt (T3+T4+T5) -----------
// M=4096 N=3072 K=2048, A[M,K] bf16, Bt[N,K] bf16; out QK (bf16, stride 2560)
// + RoPE on cols<2560, V cols>=2560 transposed to Vt. Grid 192 = 16mt x 12nt,
// XCD-swizzled (192%8==0, bijective). 512 thr = 8 waves (2M x 4N), per-wave
// 128x64 out = acc[8][4]. BK=64; LDS 128 KB = 2buf x (A 32K + B 32K).
// Per K-tile: 4 phases, each {stage 1 half-tile (2 g2l16) | ds_read subtile |
// s_barrier | lgkmcnt(0)+sched_barrier | setprio(1) 16 MFMA setprio(0) |
// s_barrier}. vmcnt(2) ONCE per tile at P0 (2 newest = next tile's A0 stage);
// never vmcnt(0) in steady state. Raw s_barrier (NOT __syncthreads - that
// drains vmcnt). Swizzle: slot s of row holds global granule s^(row&7)
// (same scheme as 2-phase kernel; staging pre-swizzles the global source).

#define G1_K  2048
#define G1_NT 32

__global__ __launch_bounds__(512, 2) void k_gemm1_256(
    const ushort_t* __restrict__ A, const ushort_t* __restrict__ Bt,
    ushort_t* __restrict__ C, const float* __restrict__ bias,
    const float* __restrict__ fc, const float* __restrict__ fs,
    ushort_t* __restrict__ Vt) {
    __shared__ __align__(16) ushort_t As[2][16384];   // 2 bufs x 256 rows x 64
    __shared__ __align__(16) ushort_t Bs[2][16384];
    int t = threadIdx.x;
    int w = t >> 6, lane = t & 63, quad = lane >> 4, l16 = lane & 15;
    int wm_i = w >> 2, wn_i = w & 3;

    int L = blockIdx.x;                    // 16 mt x 12 nt, m striped per XCD
    int xcd = L & 7, j = L >> 3;           // mper = 16/8 = 2
    int m0 = (xcd * 2 + (j & 1)) * 256;
    int n0 = (j >> 1) * 256;

    // staging: per half-tile (128 rows x 64 k), wave w call p writes rows
    // w*16+p*8 .. +7 linearly; lane's source granule pre-swizzled.
    int srow = w * 16 + (lane >> 3);
    int sg   = (lane & 7) ^ (lane >> 3);
    const ushort_t* Ag = A  + (size_t)(m0 + srow) * G1_K + sg * 8;
    const ushort_t* Bg = Bt + (size_t)(n0 + srow) * G1_K + sg * 8;

    int swz = l16 & 7;
    int cA = (quad ^ swz) * 8;             // kc=0 chunk (elem offset in row)
    int cB = ((quad + 4) ^ swz) * 8;       // kc=1

    f32x4 acc[8][4] = {};
    bf16x8 afr[4][2], bfr[4][2];

#define ST1A(KT, HA, BUF) do {                                                  \
    const ushort_t* s_ = Ag + (size_t)(HA) * 128 * G1_K + (KT) * 64;            \
    char* d_ = (char*)&As[BUF][(HA) * 8192] + w * 2048;                         \
    g2l16(s_, d_); g2l16(s_ + 8 * G1_K, d_ + 1024); } while (0)
#define ST1B(KT, HB, BUF) do {                                                  \
    const ushort_t* s_ = Bg + (size_t)(HB) * 128 * G1_K + (KT) * 64;            \
    char* d_ = (char*)&Bs[BUF][(HB) * 8192] + w * 2048;                         \
    g2l16(s_, d_); g2l16(s_ + 8 * G1_K, d_ + 1024); } while (0)

#define RDA1(MH, BUF) do {                                                      \
    const ushort_t* Ar = &As[BUF][(wm_i * 128 + (MH) * 64 + l16) * 64];         \
    _Pragma("unroll") for (int ii = 0; ii < 4; ii++) {                          \
        afr[ii][0] = *(const bf16x8*)(Ar + ii * 1024 + cA);                     \
        afr[ii][1] = *(const bf16x8*)(Ar + ii * 1024 + cB); } } while (0)
#define RDB1(NH, BUF) do {                                                      \
    const ushort_t* Br = &Bs[BUF][(wn_i * 64 + (NH) * 32 + l16) * 64];          \
    _Pragma("unroll") for (int jj = 0; jj < 2; jj++) {                          \
        bfr[(NH) * 2 + jj][0] = *(const bf16x8*)(Br + jj * 1024 + cA);          \
        bfr[(NH) * 2 + jj][1] = *(const bf16x8*)(Br + jj * 1024 + cB); } } while (0)

#define MMA1(MH, NH) do {                                                       \
    _Pragma("unroll") for (int kc = 0; kc < 2; kc++)                            \
    _Pragma("unroll") for (int ii = 0; ii < 4; ii++)                            \
    _Pragma("unroll") for (int jj = 0; jj < 2; jj++)                            \
        acc[(MH)*4+ii][(NH)*2+jj] = __builtin_amdgcn_mfma_f32_16x16x32_bf16(    \
            afr[ii][kc], bfr[(NH)*2+jj][kc], acc[(MH)*4+ii][(NH)*2+jj], 0, 0, 0); } while (0)

#define BAR1() __builtin_amdgcn_s_barrier()
#define WGK1() do { asm volatile("s_waitcnt lgkmcnt(0)" ::: "memory");          \
                    __builtin_amdgcn_sched_barrier(0); } while (0)

#define TILE1(KT, BUF, OTH) do {                                                \
    bool pf_ = (KT) + 1 < G1_NT;                                                \
    /* P0: wait tile's 8 loads (2 newest outstanding = next A0) */              \
    if (pf_) { ST1A((KT) + 1, 0, OTH);                                          \
               asm volatile("s_waitcnt vmcnt(2)" ::: "memory"); }               \
    else     { asm volatile("s_waitcnt vmcnt(0)" ::: "memory"); }               \
    BAR1();                                                                     \
    RDA1(0, BUF); RDB1(0, BUF);                                                 \
    WGK1();                                                                     \
    __builtin_amdgcn_s_setprio(1); MMA1(0, 0); __builtin_amdgcn_s_setprio(0);   \
    BAR1();                                                                     \
    /* P1 */                                                                    \
    if (pf_) ST1A((KT) + 1, 1, OTH);                                            \
    RDB1(1, BUF);                                                               \
    BAR1();                                                                     \
    WGK1();                                                                     \
    __builtin_amdgcn_s_setprio(1); MMA1(0, 1); __builtin_amdgcn_s_setprio(0);   \
    BAR1();                                                                     \
    /* P2 */                                                                    \
    if (pf_) ST1B((KT) + 1, 0, OTH);                                            \
    RDA1(1, BUF);                                                               \
    BAR1();                                                                     \
    WGK1();                                                                     \
    __builtin_amdgcn_s_setprio(1); MMA1(1, 1); __builtin_amdgcn_s_setprio(0);   \
    BAR1();                                                                     \
    /* P3: reuses bfr[0..1] (read at P0) */                                     \
    if (pf_) ST1B((KT) + 1, 1, OTH);                                            \
    BAR1();                                                                     \
    __builtin_amdgcn_s_setprio(1); MMA1(1, 0); __builtin_amdgcn_s_setprio(0);   \
    BAR1();                                                                     \
} while (0)

    // prologue: stage tile 0 (4 half-tiles, 8 loads/thread) into buf 0
    ST1A(0, 0, 0); ST1A(0, 1, 0); ST1B(0, 0, 0); ST1B(0, 1, 0);

    for (int kt = 0; kt < G1_NT; kt += 2) {
        TILE1(kt, 0, 1);
        TILE1(kt + 1, 1, 0);
    }
#undef ST1A
#undef ST1B
#undef RDA1
#undef RDB1
#undef MMA1
#undef BAR1
#undef WGK1
#undef TILE1

    // epilogue: frag (i,j2) -> r = m0+wm_i*128+i*16+quad*4, c = n0+wn_i*64+j2*16+l16
#pragma unroll
    for (int i = 0; i < 8; i++) {
        int r = m0 + wm_i * 128 + i * 16 + quad * 4;
#pragma unroll
        for (int j2 = 0; j2 < 4; j2++) {
            int c = n0 + wn_i * 64 + j2 * 16 + l16;
            float bv_ = bias[c];
            if (c >= 2560) {                          // V cols -> transposed Vt
                ushort4 pack;
                pack.x = f2bf(acc[i][j2][0] + bv_);
                pack.y = f2bf(acc[i][j2][1] + bv_);
                pack.z = f2bf(acc[i][j2][2] + bv_);
                pack.w = f2bf(acc[i][j2][3] + bv_);
                int kv = (c - 2560) >> 7, d = (c - 2560) & 127;
                int b = r >> 11, s0 = r & (S_ - 1);
                *(ushort4*)&Vt[(((size_t)b * KV_ + kv) * HD_ + d) * S_ + s0] = pack;
                continue;
            }
#pragma unroll
            for (int jr = 0; jr < 4; jr++) {
                float v = acc[i][j2][jr] + bv_;
                int s  = (r + jr) & (S_ - 1);
                int dp = (c & 127) >> 1;
                float cs = fc[s * 64 + dp], sn = fs[s * 64 + dp];
                float p = __shfl_xor(v, 1);           // pair element (c^1)
                v = (c & 1) ? (v * cs + p * sn) : (v * cs - p * sn);
                C[(size_t)(r + jr) * NQK + c] = f2bf(v);
            }
        }
    }
}

// ---------------- Flash attention v5: double-buffered staging ----------------

__global__ __launch_bounds__(512, 4) void k_flash(const ushort_t* __restrict__ QK,
                                                  const ushort_t* __restrict__ Vt,
                                                  ushort_t* __restrict__ AO) {
    __shared__ __align__(16) ushort_t Ks[2 * 8192];
    __shared__ __align__(16) ushort_t Vs[2 * 8192];
    __shared__ __align__(16) ushort_t Ps[8 * 16 * 64];
    int h = blockIdx.y, b = blockIdx.z;
    int qt = b ? ((int)gridDim.x - 1 - (int)blockIdx.x) : (int)blockIdx.x;
    int kvh = h >> 2;
    int t = threadIdx.x, w = t >> 6, lane = t & 63, quad = lane >> 4, l16 = lane & 15;
    int qrow0 = qt * 128 + w * 16;
    const float SOFT = 0.08838834764831845f * 1.4426950408889634f; // 1/sqrt(128)*log2(e)

    bf16x8 aq[4];
    {
        const ushort_t* qb = QK + (size_t)(b * S_ + qrow0 + l16) * NQK + h * HD_ + quad * 8;
#pragma unroll
        for (int kc = 0; kc < 4; kc++) aq[kc] = *(const bf16x8*)(qb + kc * 32);
    }
    bf16x8 vone;
#pragma unroll
    for (int i = 0; i < 8; i++) vone[i] = (__bf16)1.0f;

    f32x4 o[8] = {};
    f32x4 ol = {};                 // row-sum accumulator (softmax denominator)
    ushort_t* Psw = Ps + w * 16 * 64;
    int gsw = (l16 >> 1) & 3;      // read-side swizzle bits

    const ushort_t* kgb = QK + (size_t)(b * S_) * NQK + 2048 + kvh * HD_;
    const ushort_t* vgb = Vt + ((size_t)(b * KV_ + kvh) * HD_) * S_;

    int sr, sgs; char *sK0, *sV0;
    if (t < 256) {
        sr = t >> 2; sgs = (t & 3) ^ ((sr >> 1) & 3);
        sK0 = (char*)Ks + (t >> 6) * 1024;
        sV0 = nullptr;
    } else {
        int u = t - 256;
        sr = u >> 2; sgs = (u & 3) ^ ((sr >> 1) & 3);
        sV0 = (char*)Vs + ((t - 256) >> 6) * 1024;
        sK0 = nullptr;
    }

#define STAGE(KT, BUF)                                                          \
    do {                                                                        \
        if (t < 256) {                                                          \
            const ushort_t* kg = kgb + (size_t)((KT) * 64 + sr) * NQK + sgs * 8; \
            char* KsW = sK0 + (BUF) * 16384;                                    \
            _Pragma("unroll")                                                   \
            for (int p = 0; p < 4; p++) g2l16(kg + p * 32, KsW + p * 4096);     \
        } else {                                                                \
            const ushort_t* vg = vgb + (KT) * 64 + sgs * 8 + (size_t)sr * S_;   \
            char* VsW = sV0 + (BUF) * 16384;                                    \
            _Pragma("unroll")                                                   \
            for (int p = 0; p < 4; p++)                                         \
                g2l16(vg + (size_t)((p & 1) * 64) * S_ + (p >> 1) * 32, VsW + p * 4096); \
        }                                                                       \
    } while (0)

    int ktmax = 2 * qt + 1;
    STAGE(0, 0);
    __syncthreads();

    for (int kt = 0; kt <= ktmax; kt++) {
        int cur = kt & 1;
        if (kt < ktmax) STAGE(kt + 1, cur ^ 1);   // prefetch next tile

        if (kt * 64 <= qrow0 + 15) {              // else fully-masked for this wave
            const ushort_t* Kc = Ks + cur * 8192;
            const ushort_t* Vc = Vs + cur * 8192;
            f32x4 sacc[4] = {};
            __builtin_amdgcn_s_setprio(1);        // T5: favor MFMA wave (m191)
#pragma unroll
            for (int kc = 0; kc < 4; kc++)
#pragma unroll
                for (int nb = 0; nb < 4; nb++) {
                    bf16x8 bk = *(const bf16x8*)(Kc + kc * 2048 + (nb * 16 + l16) * 32 + ((quad ^ gsw) * 8));
                    sacc[nb] = __builtin_amdgcn_mfma_f32_16x16x32_bf16(aq[kc], bk, sacc[nb], 0, 0, 0);
                }
            __builtin_amdgcn_s_setprio(0);
            if (kt * 64 + 63 > qrow0) {           // diagonal tile: causal mask
#pragma unroll
                for (int nb = 0; nb < 4; nb++)
#pragma unroll
                    for (int jr = 0; jr < 4; jr++) {
                        int kcol = kt * 64 + nb * 16 + l16;
                        int qr = qrow0 + quad * 4 + jr;
                        if (kcol > qr) sacc[nb][jr] = -1e30f;
                    }
            }
#pragma unroll
            for (int nb = 0; nb < 4; nb++)
#pragma unroll
                for (int jr = 0; jr < 4; jr++)
                    Psw[(quad * 4 + jr) * 64 + nb * 16 + l16] = f2bf(exp2f(sacc[nb][jr] * SOFT));

            asm volatile("s_waitcnt lgkmcnt(0)" ::: "memory");  // P writes -> A-frag reads

            __builtin_amdgcn_s_setprio(1);        // T5: favor MFMA wave (m191)
#pragma unroll
            for (int kc2 = 0; kc2 < 2; kc2++) {
                bf16x8 ap = *(const bf16x8*)(Psw + l16 * 64 + kc2 * 32 + quad * 8);
                ol = __builtin_amdgcn_mfma_f32_16x16x32_bf16(ap, vone, ol, 0, 0, 0);
#pragma unroll
                for (int db = 0; db < 8; db++) {
                    bf16x8 bv = *(const bf16x8*)(Vc + kc2 * 4096 + (db * 16 + l16) * 32 + ((quad ^ gsw) * 8));
                    o[db] = __builtin_amdgcn_mfma_f32_16x16x32_bf16(ap, bv, o[db], 0, 0, 0);
                }
            }
            __builtin_amdgcn_s_setprio(0);
        }
        __syncthreads();   // next tile staged + this tile's LDS reads done
    }
#undef STAGE

    // epilogue: divide by l, write bf16
#pragma unroll
    for (int jr = 0; jr < 4; jr++) {
        float inv = 1.0f / ol[jr];
        size_t rbase = (size_t)(b * S_ + qrow0 + quad * 4 + jr) * D_ + h * HD_;
#pragma unroll
        for (int db = 0; db < 8; db++)
            AO[rbase + db * 16 + l16] = f2bf(o[db][jr] * inv);
    }
}

// ---------------- launch ----------------

extern "C" void kernel_launch(void* const* d_in, const int* in_sizes, int n_in,
                              void* d_out, int out_size, void* d_ws, size_t ws_size,
                              hipStream_t stream) {
    const float* x  = (const float*)d_in[0];
    // d_in[1] = mask (all zeros; reference ignores it — causal built in-kernel)
    const float* fc = (const float*)d_in[2];
    const float* fs = (const float*)d_in[3];
    const float* Wq = (const float*)d_in[4];
    const float* bq = (const float*)d_in[5];
    const float* Wk = (const float*)d_in[6];
    const float* bk = (const float*)d_in[7];
    const float* Wv = (const float*)d_in[8];
    const float* bv = (const float*)d_in[9];
    const float* Wo = (const float*)d_in[10];

    char* ws = (char*)d_ws;
    // layout (bytes); AO aliases xb (xb dead after gemm1). Vt is its own 4 MB
    // (must NOT alias Wt: gemm1 reads Wt while writing Vt). QK stride 2560.
    ushort_t* xb  = (ushort_t*)(ws);                 // 16 MB  (4096x2048 bf16)
    ushort_t* Wt  = (ushort_t*)(ws + 16777216);      // 12 MB  (3072x2048 bf16)
    ushort_t* Wot = (ushort_t*)(ws + 29360128);      //  8 MB  (2048x2048 bf16)
    float*    bb  = (float*)   (ws + 37748736);      // 12 KB
    ushort_t* QK  = (ushort_t*)(ws + 37761024);      // 20 MB  (4096x2560 bf16)
    ushort_t* Vt  = (ushort_t*)(ws + 58732544);      //  4 MB  (2*4*128*2048 bf16)
    ushort_t* AO  = xb;                              // 16 MB  (4096x2048 bf16)
    float* out = (float*)d_out;

    k_prep<<<18444, 256, 0, stream>>>(x, xb, Wq, Wk, Wv, Wo, Wt, Wot, bq, bk, bv, bb);
    k_gemm1_256<<<192, 512, 0, stream>>>(xb, Wt, QK, bb, fc, fs, Vt);
    k_flash<<<dim3(16, 16, 2), 512, 0, stream>>>(QK, Vt, AO);
    k_gemm<128><<<512, 256, 0, stream>>>(AO, Wot, out, nullptr, nullptr, nullptr, nullptr,
                                         4096, 2048, 2048, 0);
}

// Round 4
// 314.827 us; speedup vs baseline: 1.0298x; 1.0298x over previous
//
#include <hip/hip_runtime.h>

// Fused GQA attention block: QKV proj(+RoPE, +V-transpose) -> flash attn -> out proj.
// B=2 S=2048 D=2048 H=16 KV=4 HD=128. All MFMA compute in bf16 (tol = 2% of max).

#define B_  2
#define S_  2048
#define D_  2048
#define H_  16
#define KV_ 4
#define HD_ 128
#define NQK 2560    // QK buffer row stride: 2048 (Q) + 512 (K); V goes to Vt directly

typedef unsigned short ushort_t;
typedef __attribute__((ext_vector_type(8))) __bf16 bf16x8;
typedef __attribute__((ext_vector_type(4))) float  f32x4;

__device__ __forceinline__ ushort_t f2bf(float f) {
    unsigned u = __float_as_uint(f);
    u += 0x7FFFu + ((u >> 16) & 1u);          // round-to-nearest-even
    return (ushort_t)(u >> 16);
}
__device__ __forceinline__ float bf2f(ushort_t h) {
    return __uint_as_float(((unsigned)h) << 16);
}

// async global->LDS, 16B per lane; LDS dest = wave-uniform base + lane*16
__device__ __forceinline__ void g2l16(const void* g, void* l) {
    __builtin_amdgcn_global_load_lds(
        (const __attribute__((address_space(1))) unsigned int*)g,
        (__attribute__((address_space(3))) unsigned int*)l, 16, 0, 0);
}

// ---------------- fused prep: x->bf16, 4 weight transposes, bias pack -------

__global__ __launch_bounds__(256) void k_prep(
    const float* __restrict__ x,  ushort_t* __restrict__ xb,
    const float* __restrict__ Wq, const float* __restrict__ Wk,
    const float* __restrict__ Wv, const float* __restrict__ Wo,
    ushort_t* __restrict__ Wt, ushort_t* __restrict__ Wot,
    const float* __restrict__ bq, const float* __restrict__ bk,
    const float* __restrict__ bv, float* __restrict__ bb) {
    __shared__ float tile[32][33];
    int id = blockIdx.x, t = threadIdx.x;
    if (id < 8192) {                                   // x fp32 -> bf16
        int i = id * 256 + t;
        float4 v = ((const float4*)x)[i];
        ushort4 o;
        o.x = f2bf(v.x); o.y = f2bf(v.y); o.z = f2bf(v.z); o.w = f2bf(v.w);
        ((ushort4*)xb)[i] = o;
        return;
    }
    const float* src; ushort_t* dst; int C, bid;
    if (id < 12288)      { src = Wq; dst = Wt;                       C = 2048; bid = id - 8192;  }
    else if (id < 13312) { src = Wk; dst = Wt + (size_t)2048 * 2048; C = 512;  bid = id - 12288; }
    else if (id < 14336) { src = Wv; dst = Wt + (size_t)2560 * 2048; C = 512;  bid = id - 13312; }
    else if (id < 18432) { src = Wo; dst = Wot;                      C = 2048; bid = id - 14336; }
    else {                                             // bias pack
        int i = (id - 18432) * 256 + t;
        if (i < 3072)
            bb[i] = (i < 2048) ? bq[i] : (i < 2560) ? bk[i - 2048] : bv[i - 2560];
        return;
    }
    const int R = 2048;
    int nbc = C >> 5;
    int c0 = (bid % nbc) * 32, r0 = (bid / nbc) * 32;
    int tx = t & 31, ty = t >> 5;
    for (int i = ty; i < 32; i += 8)
        tile[i][tx] = src[(size_t)(r0 + i) * C + c0 + tx];
    __syncthreads();
    for (int i = ty; i < 32; i += 8)
        dst[(size_t)(c0 + i) * R + r0 + tx] = f2bf(tile[tx][i]);
}

// ---------------- gemm2: 128x128 tile, 2-phase (unchanged, out proj only) ---

template<int BK>
__global__ __launch_bounds__(256, 3) void k_gemm(const ushort_t* __restrict__ A,
                                                 const ushort_t* __restrict__ Bt,
                                                 void* __restrict__ Cp,
                                                 const float* __restrict__ bias,
                                                 const float* __restrict__ fc,
                                                 const float* __restrict__ fs,
                                                 ushort_t* __restrict__ Vt,
                                                 int M, int N, int K, int out_bf16) {
    constexpr int GPR    = BK / 8;    // 16B granules per row
    constexpr int RPR    = 64 / GPR;  // rows staged per round per wave
    constexpr int ROUNDS = 32 / RPR;  // rounds to cover 32 rows per wave
    __shared__ __align__(16) ushort_t As[128 * BK];
    __shared__ __align__(16) ushort_t Bs[128 * BK];
    int t = threadIdx.x;
    int w = t >> 6, lane = t & 63, quad = lane >> 4, l16 = lane & 15;
    int L = blockIdx.x;
    int mper = (M >> 7) >> 3;                 // m-tiles per XCD
    int xcd = L & 7, j = L >> 3;
    int m0 = (xcd * mper + (j % mper)) * 128;
    int n0 = (j / mper) * 128;
    int wm = (w >> 1) * 64, wn = (w & 1) * 64;
    f32x4 acc[4][4] = {};

    int rlo = lane / GPR;                     // row-within-round
    int gsl = lane & (GPR - 1);               // slot granule
    const ushort_t* Ag = A  + (size_t)(m0 + w * 32) * K;
    const ushort_t* Bg = Bt + (size_t)(n0 + w * 32) * K;
    int rsw = (l16 & 7);                      // read-side swizzle bits

    for (int k0 = 0; k0 < K; k0 += BK) {
        __syncthreads();
#pragma unroll
        for (int p = 0; p < ROUNDS; p++) {
            int row = p * RPR + rlo;
            int gs = gsl ^ (row & 7);
            g2l16(Ag + (size_t)row * K + k0 + gs * 8, (char*)As + (w * 32 + p * RPR) * 2 * BK);
            g2l16(Bg + (size_t)row * K + k0 + gs * 8, (char*)Bs + (w * 32 + p * RPR) * 2 * BK);
        }
        __syncthreads();
#pragma unroll
        for (int kc = 0; kc < BK / 32; kc++) {
            int gg = quad + kc * 4;
            bf16x8 af[4], bfr[4];
#pragma unroll
            for (int i = 0; i < 4; i++)
                af[i] = *(const bf16x8*)(As + (wm + i * 16 + l16) * BK + ((gg ^ rsw) * 8));
#pragma unroll
            for (int j2 = 0; j2 < 4; j2++)
                bfr[j2] = *(const bf16x8*)(Bs + (wn + j2 * 16 + l16) * BK + ((gg ^ rsw) * 8));
#pragma unroll
            for (int i = 0; i < 4; i++)
#pragma unroll
                for (int j2 = 0; j2 < 4; j2++)
                    acc[i][j2] = __builtin_amdgcn_mfma_f32_16x16x32_bf16(af[i], bfr[j2], acc[i][j2], 0, 0, 0);
        }
    }
    int ostride = fc ? NQK : N;
#pragma unroll
    for (int i = 0; i < 4; i++) {
        int r = m0 + wm + i * 16 + quad * 4;
#pragma unroll
        for (int j2 = 0; j2 < 4; j2++) {
            int c = n0 + wn + j2 * 16 + l16;
            float bv_ = bias ? bias[c] : 0.f;
            if (fc && c >= 2560) {
                ushort4 pack;
                pack.x = f2bf(acc[i][j2][0] + bv_);
                pack.y = f2bf(acc[i][j2][1] + bv_);
                pack.z = f2bf(acc[i][j2][2] + bv_);
                pack.w = f2bf(acc[i][j2][3] + bv_);
                int kv = (c - 2560) >> 7, d = (c - 2560) & 127;
                int b = r >> 11, s0 = r & (S_ - 1);
                *(ushort4*)&Vt[(((size_t)b * KV_ + kv) * HD_ + d) * S_ + s0] = pack;
                continue;
            }
#pragma unroll
            for (int jr = 0; jr < 4; jr++) {
                float v = acc[i][j2][jr] + bv_;
                if (fc) {
                    int s  = (r + jr) & (S_ - 1);
                    int dp = (c & 127) >> 1;
                    float cs = fc[s * 64 + dp], sn = fs[s * 64 + dp];
                    float p = __shfl_xor(v, 1);
                    v = (c & 1) ? (v * cs + p * sn) : (v * cs - p * sn);
                }
                if (out_bf16) ((ushort_t*)Cp)[(size_t)(r + jr) * ostride + c] = f2bf(v);
                else          ((float*)Cp)[(size_t)(r + jr) * ostride + c] = v;
            }
        }
    }
}

// ---------------- gemm1: 256x256 8-phase counted-vmcnt (T3+T4+T5), v2 -------
// Round-2 post-mortem: v1 regressed (82us, MfmaUtil 24%) because the prefetch
// distance was ~1 phase at the wait point -> full HBM latency exposed per
// K-tile. v2 uses the m201-faithful deep stream: stage order per tile
// {B0,B1,A0,A1}; single vmcnt(4) per tile at P4, issued >=2 phases (~1200cyc
// MFMA) after the newest load it covers, leaving 2 half-tiles (4 loads) in
// flight across the barrier.
// Audited (r3): barrier-uniform control flow (no divergent s_barrier);
// vmcnt queue walked at every tile boundary; all region restage-vs-read
// hazards protected by each wave's lgkmcnt(0)-before-barrier-arrival;
// bfr[0..1] register (not LDS) carry from P1 to P4.
// Per-tile schedule (tile n, buf=n&1, obuf=!buf):
//   P1: rd A0q,B0q(buf); st t(n+1).A0->obuf | P2: rd B1q; st t(n+1).A1->obuf
//   P3: rd A1q; st t(n+2).B0->buf          | P4: cached; st t(n+2).B1->buf;
//                                            vmcnt(4) [tile n+1 landed]
// Prologue: t0.{B0,B1,A0,A1}, t1.{B0,B1}; vmcnt(4). Epilogue: vmcnt(0) from
// tile NT-2; stage guards skip out-of-range tiles.

#define G1_K  2048
#define G1_NT 32

__global__ __launch_bounds__(512, 2) void k_gemm1_256(
    const ushort_t* __restrict__ A, const ushort_t* __restrict__ Bt,
    ushort_t* __restrict__ C, const float* __restrict__ bias,
    const float* __restrict__ fc, const float* __restrict__ fs,
    ushort_t* __restrict__ Vt) {
    __shared__ __align__(16) ushort_t As[2][16384];   // 2 bufs x 256 rows x 64
    __shared__ __align__(16) ushort_t Bs[2][16384];
    int t = threadIdx.x;
    int w = t >> 6, lane = t & 63, quad = lane >> 4, l16 = lane & 15;
    int wm_i = w >> 2, wn_i = w & 3;

    int L = blockIdx.x;                    // 16 mt x 12 nt, m striped per XCD
    int xcd = L & 7, j = L >> 3;           // mper = 16/8 = 2
    int m0 = (xcd * 2 + (j & 1)) * 256;
    int n0 = (j >> 1) * 256;

    // staging: per half-tile (128 rows x 64 k), wave w writes rows w*16..+15
    // linearly; lane's global source granule pre-swizzled: slot s of row r
    // holds global granule s^(r&7).
    int srow = w * 16 + (lane >> 3);
    int sg   = (lane & 7) ^ (lane >> 3);
    const ushort_t* Ag = A  + (size_t)(m0 + srow) * G1_K + sg * 8;
    const ushort_t* Bg = Bt + (size_t)(n0 + srow) * G1_K + sg * 8;

    int swz = l16 & 7;
    int cA = (quad ^ swz) * 8;             // kc=0 chunk (elem offset in row)
    int cB = ((quad + 4) ^ swz) * 8;       // kc=1

    f32x4 acc[8][4] = {};
    bf16x8 afr[4][2], bfr[4][2];

#define ST1A(KT, HA, BUF) do {                                                  \
    const ushort_t* s_ = Ag + (size_t)(HA) * 128 * G1_K + (KT) * 64;            \
    char* d_ = (char*)&As[BUF][(HA) * 8192] + w * 2048;                         \
    g2l16(s_, d_); g2l16(s_ + 8 * G1_K, d_ + 1024); } while (0)
#define ST1B(KT, HB, BUF) do {                                                  \
    const ushort_t* s_ = Bg + (size_t)(HB) * 128 * G1_K + (KT) * 64;            \
    char* d_ = (char*)&Bs[BUF][(HB) * 8192] + w * 2048;                         \
    g2l16(s_, d_); g2l16(s_ + 8 * G1_K, d_ + 1024); } while (0)

#define RDA1(MH, BUF) do {                                                      \
    const ushort_t* Ar = &As[BUF][(wm_i * 128 + (MH) * 64 + l16) * 64];         \
    _Pragma("unroll") for (int ii = 0; ii < 4; ii++) {                          \
        afr[ii][0] = *(const bf16x8*)(Ar + ii * 1024 + cA);                     \
        afr[ii][1] = *(const bf16x8*)(Ar + ii * 1024 + cB); } } while (0)
#define RDB1(NH, BUF) do {                                                      \
    const ushort_t* Br = &Bs[BUF][(wn_i * 64 + (NH) * 32 + l16) * 64];          \
    _Pragma("unroll") for (int jj = 0; jj < 2; jj++) {                          \
        bfr[(NH) * 2 + jj][0] = *(const bf16x8*)(Br + jj * 1024 + cA);          \
        bfr[(NH) * 2 + jj][1] = *(const bf16x8*)(Br + jj * 1024 + cB); } } while (0)

#define MMA1(MH, NH) do {                                                       \
    _Pragma("unroll") for (int kc = 0; kc < 2; kc++)                            \
    _Pragma("unroll") for (int ii = 0; ii < 4; ii++)                            \
    _Pragma("unroll") for (int jj = 0; jj < 2; jj++)                            \
        acc[(MH)*4+ii][(NH)*2+jj] = __builtin_amdgcn_mfma_f32_16x16x32_bf16(    \
            afr[ii][kc], bfr[(NH)*2+jj][kc], acc[(MH)*4+ii][(NH)*2+jj], 0, 0, 0); } while (0)

#define BAR1() __builtin_amdgcn_s_barrier()
#define WGK1() do { asm volatile("s_waitcnt lgkmcnt(0)" ::: "memory");          \
                    __builtin_amdgcn_sched_barrier(0); } while (0)

#define TILE1(KT, BUF, OTH) do {                                                \
    /* P1: read A0-quad + B0-quad; stage tile KT+1's A0 -> other buf */         \
    RDA1(0, BUF); RDB1(0, BUF);                                                 \
    if ((KT) + 1 < G1_NT) ST1A((KT) + 1, 0, OTH);                               \
    BAR1(); WGK1();                                                             \
    __builtin_amdgcn_s_setprio(1); MMA1(0, 0); __builtin_amdgcn_s_setprio(0);   \
    BAR1();                                                                     \
    /* P2: read B1-quad; stage tile KT+1's A1 -> other buf */                   \
    RDB1(1, BUF);                                                               \
    if ((KT) + 1 < G1_NT) ST1A((KT) + 1, 1, OTH);                               \
    BAR1(); WGK1();                                                             \
    __builtin_amdgcn_s_setprio(1); MMA1(0, 1); __builtin_amdgcn_s_setprio(0);   \
    BAR1();                                                                     \
    /* P3: read A1-quad; stage tile KT+2's B0 -> this buf (B reads done P2) */  \
    RDA1(1, BUF);                                                               \
    if ((KT) + 2 < G1_NT) ST1B((KT) + 2, 0, BUF);                               \
    BAR1(); WGK1();                                                             \
    __builtin_amdgcn_s_setprio(1); MMA1(1, 1); __builtin_amdgcn_s_setprio(0);   \
    BAR1();                                                                     \
    /* P4: cached regs; stage tile KT+2's B1; tile-boundary counted wait */     \
    if ((KT) + 2 < G1_NT) ST1B((KT) + 2, 1, BUF);                               \
    if ((KT) < G1_NT - 2) asm volatile("s_waitcnt vmcnt(4)" ::: "memory");      \
    else                  asm volatile("s_waitcnt vmcnt(0)" ::: "memory");      \
    BAR1();                                                                     \
    __builtin_amdgcn_s_setprio(1); MMA1(1, 0); __builtin_amdgcn_s_setprio(0);   \
    BAR1();                                                                     \
} while (0)

    // prologue: tile0 {B0,B1,A0,A1} -> buf0, tile1 {B0,B1} -> buf1 (12 loads);
    // vmcnt(4): tile0 fully landed, tile1's B halves in flight.
    ST1B(0, 0, 0); ST1B(0, 1, 0); ST1A(0, 0, 0); ST1A(0, 1, 0);
    ST1B(1, 0, 1); ST1B(1, 1, 1);
    asm volatile("s_waitcnt vmcnt(4)" ::: "memory");
    BAR1();

    for (int kt = 0; kt < G1_NT; kt += 2) {
        TILE1(kt, 0, 1);
        TILE1(kt + 1, 1, 0);
    }
#undef ST1A
#undef ST1B
#undef RDA1
#undef RDB1
#undef MMA1
#undef BAR1
#undef WGK1
#undef TILE1

    // epilogue: frag (i,j2) -> r = m0+wm_i*128+i*16+quad*4, c = n0+wn_i*64+j2*16+l16
#pragma unroll
    for (int i = 0; i < 8; i++) {
        int r = m0 + wm_i * 128 + i * 16 + quad * 4;
#pragma unroll
        for (int j2 = 0; j2 < 4; j2++) {
            int c = n0 + wn_i * 64 + j2 * 16 + l16;
            float bv_ = bias[c];
            if (c >= 2560) {                          // V cols -> transposed Vt
                ushort4 pack;
                pack.x = f2bf(acc[i][j2][0] + bv_);
                pack.y = f2bf(acc[i][j2][1] + bv_);
                pack.z = f2bf(acc[i][j2][2] + bv_);
                pack.w = f2bf(acc[i][j2][3] + bv_);
                int kv = (c - 2560) >> 7, d = (c - 2560) & 127;
                int b = r >> 11, s0 = r & (S_ - 1);
                *(ushort4*)&Vt[(((size_t)b * KV_ + kv) * HD_ + d) * S_ + s0] = pack;
                continue;
            }
#pragma unroll
            for (int jr = 0; jr < 4; jr++) {
                float v = acc[i][j2][jr] + bv_;
                int s  = (r + jr) & (S_ - 1);
                int dp = (c & 127) >> 1;
                float cs = fc[s * 64 + dp], sn = fs[s * 64 + dp];
                float p = __shfl_xor(v, 1);           // pair element (c^1)
                v = (c & 1) ? (v * cs + p * sn) : (v * cs - p * sn);
                C[(size_t)(r + jr) * NQK + c] = f2bf(v);
            }
        }
    }
}

// ---------------- Flash attention v5: double-buffered staging ----------------

__global__ __launch_bounds__(512, 4) void k_flash(const ushort_t* __restrict__ QK,
                                                  const ushort_t* __restrict__ Vt,
                                                  ushort_t* __restrict__ AO) {
    __shared__ __align__(16) ushort_t Ks[2 * 8192];
    __shared__ __align__(16) ushort_t Vs[2 * 8192];
    __shared__ __align__(16) ushort_t Ps[8 * 16 * 64];
    int h = blockIdx.y, b = blockIdx.z;
    int qt = b ? ((int)gridDim.x - 1 - (int)blockIdx.x) : (int)blockIdx.x;
    int kvh = h >> 2;
    int t = threadIdx.x, w = t >> 6, lane = t & 63, quad = lane >> 4, l16 = lane & 15;
    int qrow0 = qt * 128 + w * 16;
    const float SOFT = 0.08838834764831845f * 1.4426950408889634f; // 1/sqrt(128)*log2(e)

    bf16x8 aq[4];
    {
        const ushort_t* qb = QK + (size_t)(b * S_ + qrow0 + l16) * NQK + h * HD_ + quad * 8;
#pragma unroll
        for (int kc = 0; kc < 4; kc++) aq[kc] = *(const bf16x8*)(qb + kc * 32);
    }
    bf16x8 vone;
#pragma unroll
    for (int i = 0; i < 8; i++) vone[i] = (__bf16)1.0f;

    f32x4 o[8] = {};
    f32x4 ol = {};                 // row-sum accumulator (softmax denominator)
    ushort_t* Psw = Ps + w * 16 * 64;
    int gsw = (l16 >> 1) & 3;      // read-side swizzle bits

    const ushort_t* kgb = QK + (size_t)(b * S_) * NQK + 2048 + kvh * HD_;
    const ushort_t* vgb = Vt + ((size_t)(b * KV_ + kvh) * HD_) * S_;

    int sr, sgs; char *sK0, *sV0;
    if (t < 256) {
        sr = t >> 2; sgs = (t & 3) ^ ((sr >> 1) & 3);
        sK0 = (char*)Ks + (t >> 6) * 1024;
        sV0 = nullptr;
    } else {
        int u = t - 256;
        sr = u >> 2; sgs = (u & 3) ^ ((sr >> 1) & 3);
        sV0 = (char*)Vs + ((t - 256) >> 6) * 1024;
        sK0 = nullptr;
    }

#define STAGE(KT, BUF)                                                          \
    do {                                                                        \
        if (t < 256) {                                                          \
            const ushort_t* kg = kgb + (size_t)((KT) * 64 + sr) * NQK + sgs * 8; \
            char* KsW = sK0 + (BUF) * 16384;                                    \
            _Pragma("unroll")                                                   \
            for (int p = 0; p < 4; p++) g2l16(kg + p * 32, KsW + p * 4096);     \
        } else {                                                                \
            const ushort_t* vg = vgb + (KT) * 64 + sgs * 8 + (size_t)sr * S_;   \
            char* VsW = sV0 + (BUF) * 16384;                                    \
            _Pragma("unroll")                                                   \
            for (int p = 0; p < 4; p++)                                         \
                g2l16(vg + (size_t)((p & 1) * 64) * S_ + (p >> 1) * 32, VsW + p * 4096); \
        }                                                                       \
    } while (0)

    int ktmax = 2 * qt + 1;
    STAGE(0, 0);
    __syncthreads();

    for (int kt = 0; kt <= ktmax; kt++) {
        int cur = kt & 1;
        if (kt < ktmax) STAGE(kt + 1, cur ^ 1);   // prefetch next tile

        if (kt * 64 <= qrow0 + 15) {              // else fully-masked for this wave
            const ushort_t* Kc = Ks + cur * 8192;
            const ushort_t* Vc = Vs + cur * 8192;
            f32x4 sacc[4] = {};
            __builtin_amdgcn_s_setprio(1);        // T5: favor MFMA wave (m191)
#pragma unroll
            for (int kc = 0; kc < 4; kc++)
#pragma unroll
                for (int nb = 0; nb < 4; nb++) {
                    bf16x8 bk = *(const bf16x8*)(Kc + kc * 2048 + (nb * 16 + l16) * 32 + ((quad ^ gsw) * 8));
                    sacc[nb] = __builtin_amdgcn_mfma_f32_16x16x32_bf16(aq[kc], bk, sacc[nb], 0, 0, 0);
                }
            __builtin_amdgcn_s_setprio(0);
            if (kt * 64 + 63 > qrow0) {           // diagonal tile: causal mask
#pragma unroll
                for (int nb = 0; nb < 4; nb++)
#pragma unroll
                    for (int jr = 0; jr < 4; jr++) {
                        int kcol = kt * 64 + nb * 16 + l16;
                        int qr = qrow0 + quad * 4 + jr;
                        if (kcol > qr) sacc[nb][jr] = -1e30f;
                    }
            }
#pragma unroll
            for (int nb = 0; nb < 4; nb++)
#pragma unroll
                for (int jr = 0; jr < 4; jr++)
                    Psw[(quad * 4 + jr) * 64 + nb * 16 + l16] = f2bf(exp2f(sacc[nb][jr] * SOFT));

            asm volatile("s_waitcnt lgkmcnt(0)" ::: "memory");  // P writes -> A-frag reads

            __builtin_amdgcn_s_setprio(1);        // T5: favor MFMA wave (m191)
#pragma unroll
            for (int kc2 = 0; kc2 < 2; kc2++) {
                bf16x8 ap = *(const bf16x8*)(Psw + l16 * 64 + kc2 * 32 + quad * 8);
                ol = __builtin_amdgcn_mfma_f32_16x16x32_bf16(ap, vone, ol, 0, 0, 0);
#pragma unroll
                for (int db = 0; db < 8; db++) {
                    bf16x8 bv = *(const bf16x8*)(Vc + kc2 * 4096 + (db * 16 + l16) * 32 + ((quad ^ gsw) * 8));
                    o[db] = __builtin_amdgcn_mfma_f32_16x16x32_bf16(ap, bv, o[db], 0, 0, 0);
                }
            }
            __builtin_amdgcn_s_setprio(0);
        }
        __syncthreads();   // next tile staged + this tile's LDS reads done
    }
#undef STAGE

    // epilogue: divide by l, write bf16
#pragma unroll
    for (int jr = 0; jr < 4; jr++) {
        float inv = 1.0f / ol[jr];
        size_t rbase = (size_t)(b * S_ + qrow0 + quad * 4 + jr) * D_ + h * HD_;
#pragma unroll
        for (int db = 0; db < 8; db++)
            AO[rbase + db * 16 + l16] = f2bf(o[db][jr] * inv);
    }
}

// ---------------- launch ----------------

extern "C" void kernel_launch(void* const* d_in, const int* in_sizes, int n_in,
                              void* d_out, int out_size, void* d_ws, size_t ws_size,
                              hipStream_t stream) {
    const float* x  = (const float*)d_in[0];
    // d_in[1] = mask (all zeros; reference ignores it — causal built in-kernel)
    const float* fc = (const float*)d_in[2];
    const float* fs = (const float*)d_in[3];
    const float* Wq = (const float*)d_in[4];
    const float* bq = (const float*)d_in[5];
    const float* Wk = (const float*)d_in[6];
    const float* bk = (const float*)d_in[7];
    const float* Wv = (const float*)d_in[8];
    const float* bv = (const float*)d_in[9];
    const float* Wo = (const float*)d_in[10];

    char* ws = (char*)d_ws;
    // layout (bytes); AO aliases xb (xb dead after gemm1). Vt is its own 4 MB
    // (must NOT alias Wt: gemm1 reads Wt while writing Vt). QK stride 2560.
    ushort_t* xb  = (ushort_t*)(ws);                 // 16 MB  (4096x2048 bf16)
    ushort_t* Wt  = (ushort_t*)(ws + 16777216);      // 12 MB  (3072x2048 bf16)
    ushort_t* Wot = (ushort_t*)(ws + 29360128);      //  8 MB  (2048x2048 bf16)
    float*    bb  = (float*)   (ws + 37748736);      // 12 KB
    ushort_t* QK  = (ushort_t*)(ws + 37761024);      // 20 MB  (4096x2560 bf16)
    ushort_t* Vt  = (ushort_t*)(ws + 58732544);      //  4 MB  (2*4*128*2048 bf16)
    ushort_t* AO  = xb;                              // 16 MB  (4096x2048 bf16)
    float* out = (float*)d_out;

    k_prep<<<18444, 256, 0, stream>>>(x, xb, Wq, Wk, Wv, Wo, Wt, Wot, bq, bk, bv, bb);
    k_gemm1_256<<<192, 512, 0, stream>>>(xb, Wt, QK, bb, fc, fs, Vt);
    k_flash<<<dim3(16, 16, 2), 512, 0, stream>>>(QK, Vt, AO);
    k_gemm<128><<<512, 256, 0, stream>>>(AO, Wot, out, nullptr, nullptr, nullptr, nullptr,
                                         4096, 2048, 2048, 0);
}

// Round 5
// 305.763 us; speedup vs baseline: 1.0603x; 1.0296x over previous
//
#include <hip/hip_runtime.h>

// Fused GQA attention block: QKV proj(+RoPE, +V-transpose) -> flash attn -> out proj.
// B=2 S=2048 D=2048 H=16 KV=4 HD=128. All MFMA compute in bf16 (tol = 2% of max).

#define B_  2
#define S_  2048
#define D_  2048
#define H_  16
#define KV_ 4
#define HD_ 128
#define NQK 2560    // QK buffer row stride: 2048 (Q) + 512 (K); V goes to Vt directly

typedef unsigned short ushort_t;
typedef __attribute__((ext_vector_type(8))) __bf16 bf16x8;
typedef __attribute__((ext_vector_type(4))) float  f32x4;

__device__ __forceinline__ ushort_t f2bf(float f) {
    unsigned u = __float_as_uint(f);
    u += 0x7FFFu + ((u >> 16) & 1u);          // round-to-nearest-even
    return (ushort_t)(u >> 16);
}
__device__ __forceinline__ float bf2f(ushort_t h) {
    return __uint_as_float(((unsigned)h) << 16);
}

// async global->LDS, 16B per lane; LDS dest = wave-uniform base + lane*16
__device__ __forceinline__ void g2l16(const void* g, void* l) {
    __builtin_amdgcn_global_load_lds(
        (const __attribute__((address_space(1))) unsigned int*)g,
        (__attribute__((address_space(3))) unsigned int*)l, 16, 0, 0);
}

// ---------------- fused prep: x->bf16, 4 weight transposes, bias pack -------

__global__ __launch_bounds__(256) void k_prep(
    const float* __restrict__ x,  ushort_t* __restrict__ xb,
    const float* __restrict__ Wq, const float* __restrict__ Wk,
    const float* __restrict__ Wv, const float* __restrict__ Wo,
    ushort_t* __restrict__ Wt, ushort_t* __restrict__ Wot,
    const float* __restrict__ bq, const float* __restrict__ bk,
    const float* __restrict__ bv, float* __restrict__ bb) {
    __shared__ float tile[32][33];
    int id = blockIdx.x, t = threadIdx.x;
    if (id < 8192) {                                   // x fp32 -> bf16
        int i = id * 256 + t;
        float4 v = ((const float4*)x)[i];
        ushort4 o;
        o.x = f2bf(v.x); o.y = f2bf(v.y); o.z = f2bf(v.z); o.w = f2bf(v.w);
        ((ushort4*)xb)[i] = o;
        return;
    }
    const float* src; ushort_t* dst; int C, bid;
    if (id < 12288)      { src = Wq; dst = Wt;                       C = 2048; bid = id - 8192;  }
    else if (id < 13312) { src = Wk; dst = Wt + (size_t)2048 * 2048; C = 512;  bid = id - 12288; }
    else if (id < 14336) { src = Wv; dst = Wt + (size_t)2560 * 2048; C = 512;  bid = id - 13312; }
    else if (id < 18432) { src = Wo; dst = Wot;                      C = 2048; bid = id - 14336; }
    else {                                             // bias pack
        int i = (id - 18432) * 256 + t;
        if (i < 3072)
            bb[i] = (i < 2048) ? bq[i] : (i < 2560) ? bk[i - 2048] : bv[i - 2560];
        return;
    }
    const int R = 2048;
    int nbc = C >> 5;
    int c0 = (bid % nbc) * 32, r0 = (bid / nbc) * 32;
    int tx = t & 31, ty = t >> 5;
    for (int i = ty; i < 32; i += 8)
        tile[i][tx] = src[(size_t)(r0 + i) * C + c0 + tx];
    __syncthreads();
    for (int i = ty; i < 32; i += 8)
        dst[(size_t)(c0 + i) * R + r0 + tx] = f2bf(tile[tx][i]);
}

// ---------------- gemm2: 128x128 tile, 2-phase (unchanged, out proj only) ---

template<int BK>
__global__ __launch_bounds__(256, 3) void k_gemm(const ushort_t* __restrict__ A,
                                                 const ushort_t* __restrict__ Bt,
                                                 void* __restrict__ Cp,
                                                 const float* __restrict__ bias,
                                                 const float* __restrict__ fc,
                                                 const float* __restrict__ fs,
                                                 ushort_t* __restrict__ Vt,
                                                 int M, int N, int K, int out_bf16) {
    constexpr int GPR    = BK / 8;    // 16B granules per row
    constexpr int RPR    = 64 / GPR;  // rows staged per round per wave
    constexpr int ROUNDS = 32 / RPR;  // rounds to cover 32 rows per wave
    __shared__ __align__(16) ushort_t As[128 * BK];
    __shared__ __align__(16) ushort_t Bs[128 * BK];
    int t = threadIdx.x;
    int w = t >> 6, lane = t & 63, quad = lane >> 4, l16 = lane & 15;
    int L = blockIdx.x;
    int mper = (M >> 7) >> 3;                 // m-tiles per XCD
    int xcd = L & 7, j = L >> 3;
    int m0 = (xcd * mper + (j % mper)) * 128;
    int n0 = (j / mper) * 128;
    int wm = (w >> 1) * 64, wn = (w & 1) * 64;
    f32x4 acc[4][4] = {};

    int rlo = lane / GPR;                     // row-within-round
    int gsl = lane & (GPR - 1);               // slot granule
    const ushort_t* Ag = A  + (size_t)(m0 + w * 32) * K;
    const ushort_t* Bg = Bt + (size_t)(n0 + w * 32) * K;
    int rsw = (l16 & 7);                      // read-side swizzle bits

    for (int k0 = 0; k0 < K; k0 += BK) {
        __syncthreads();
#pragma unroll
        for (int p = 0; p < ROUNDS; p++) {
            int row = p * RPR + rlo;
            int gs = gsl ^ (row & 7);
            g2l16(Ag + (size_t)row * K + k0 + gs * 8, (char*)As + (w * 32 + p * RPR) * 2 * BK);
            g2l16(Bg + (size_t)row * K + k0 + gs * 8, (char*)Bs + (w * 32 + p * RPR) * 2 * BK);
        }
        __syncthreads();
#pragma unroll
        for (int kc = 0; kc < BK / 32; kc++) {
            int gg = quad + kc * 4;
            bf16x8 af[4], bfr[4];
#pragma unroll
            for (int i = 0; i < 4; i++)
                af[i] = *(const bf16x8*)(As + (wm + i * 16 + l16) * BK + ((gg ^ rsw) * 8));
#pragma unroll
            for (int j2 = 0; j2 < 4; j2++)
                bfr[j2] = *(const bf16x8*)(Bs + (wn + j2 * 16 + l16) * BK + ((gg ^ rsw) * 8));
#pragma unroll
            for (int i = 0; i < 4; i++)
#pragma unroll
                for (int j2 = 0; j2 < 4; j2++)
                    acc[i][j2] = __builtin_amdgcn_mfma_f32_16x16x32_bf16(af[i], bfr[j2], acc[i][j2], 0, 0, 0);
        }
    }
    int ostride = fc ? NQK : N;
#pragma unroll
    for (int i = 0; i < 4; i++) {
        int r = m0 + wm + i * 16 + quad * 4;
#pragma unroll
        for (int j2 = 0; j2 < 4; j2++) {
            int c = n0 + wn + j2 * 16 + l16;
            float bv_ = bias ? bias[c] : 0.f;
            if (fc && c >= 2560) {
                ushort4 pack;
                pack.x = f2bf(acc[i][j2][0] + bv_);
                pack.y = f2bf(acc[i][j2][1] + bv_);
                pack.z = f2bf(acc[i][j2][2] + bv_);
                pack.w = f2bf(acc[i][j2][3] + bv_);
                int kv = (c - 2560) >> 7, d = (c - 2560) & 127;
                int b = r >> 11, s0 = r & (S_ - 1);
                *(ushort4*)&Vt[(((size_t)b * KV_ + kv) * HD_ + d) * S_ + s0] = pack;
                continue;
            }
#pragma unroll
            for (int jr = 0; jr < 4; jr++) {
                float v = acc[i][j2][jr] + bv_;
                if (fc) {
                    int s  = (r + jr) & (S_ - 1);
                    int dp = (c & 127) >> 1;
                    float cs = fc[s * 64 + dp], sn = fs[s * 64 + dp];
                    float p = __shfl_xor(v, 1);
                    v = (c & 1) ? (v * cs + p * sn) : (v * cs - p * sn);
                }
                if (out_bf16) ((ushort_t*)Cp)[(size_t)(r + jr) * ostride + c] = f2bf(v);
                else          ((float*)Cp)[(size_t)(r + jr) * ostride + c] = v;
            }
        }
    }
}

// ---------------- gemm1: 256x192 8-phase counted-vmcnt, v3 ------------------
// Round-4 post-mortem: v2 (256x256, grid 192) ran 77.5us at MfmaUtil 26%, but
// per-ACTIVE-CU it was 35.6% of peak vs the old 128^2 kernel's 28% -- the
// loss was 64 idle CUs (192 blocks on 256 CUs). v3: tile 256x192 -> grid
// 16mt x 16nt = 256 blocks = exact machine fill (and 256%8==0, swizzle stays
// bijective). Per-wave 128x48 out = acc[8][3]. B staged as 3 thirds of 64
// rows (8KB = exactly 1 g2l16/thread -- UNIFORM per-thread load counts, so
// vmcnt(N) semantics hold for every wave). A staged as 2 halves (2 loads/thr).
// Per-tile schedule (tile n, buf=n&1, oth=!buf), 4 phases x {reads, stage,
// bar, lgkm0+schedbar, setprio MFMA, bar}:
//   P1: rd afr(M0)+bfr(g0); st t(n+1).A0->oth   MMA(0,g0)         [8]
//   P2: rd bfr(g1),bfr(g2); st t(n+1).A1->oth   MMA(0,g1)+(0,g2) [16]
//   P3: rd afr(M1);  st t(n+2).B0,B1->buf       MMA(1,g2)+(1,g1) [16]
//   P4: st t(n+2).B2->buf; vmcnt(3)             MMA(1,g0)         [8]
// vmcnt(3) at P4 leaves t(n+2).B (3 loads) in flight; guarantees all of
// t(n+1) landed. Restage-vs-read: every region's reads drained by each
// wave's lgkmcnt(0) before its first phase barrier; restage issue is >=1
// barrier later (A regions: last read P3, restaged next-tile P1/P2; B
// regions: last read P2, restaged P3/P4). Prologue: t0.{B0,B1,B2,A0,A1}
// ->buf0, t1.{B0,B1,B2}->buf1 (10 loads/thr), vmcnt(3). Epilogue: vmcnt(0)
// from tile NT-2.

#define G1_K  2048
#define G1_NT 32

__global__ __launch_bounds__(512, 2) void k_gemm1_256(
    const ushort_t* __restrict__ A, const ushort_t* __restrict__ Bt,
    ushort_t* __restrict__ C, const float* __restrict__ bias,
    const float* __restrict__ fc, const float* __restrict__ fs,
    ushort_t* __restrict__ Vt) {
    __shared__ __align__(16) ushort_t As[2][16384];   // 2 bufs x 256 rows x 64
    __shared__ __align__(16) ushort_t Bs[2][12288];   // 2 bufs x 192 rows x 64
    int t = threadIdx.x;
    int w = t >> 6, lane = t & 63, quad = lane >> 4, l16 = lane & 15;
    int wm_i = w >> 2, wn_i = w & 3;

    int L = blockIdx.x;                    // 16 mt x 16 nt, m striped per XCD
    int xcd = L & 7, j = L >> 3;           // mper = 16/8 = 2
    int m0 = (xcd * 2 + (j & 1)) * 256;
    int n0 = (j >> 1) * 192;

    // A staging: half-tile = 128 rows x 64 k; wave w writes rows w*16..+15
    // (2 loads: +0, +8 rows). B staging: third = 64 rows; wave w writes rows
    // w*8..+7 (1 load). Global source granule pre-swizzled: LDS slot s of
    // row r holds global granule s^(r&7)  (row&7 invariant under +8/+16/+64).
    int srow = w * 16 + (lane >> 3);
    int sg   = (lane & 7) ^ (lane >> 3);
    const ushort_t* Ag  = A  + (size_t)(m0 + srow) * G1_K + sg * 8;
    const ushort_t* Bg3 = Bt + (size_t)(n0 + w * 8 + (lane >> 3)) * G1_K + sg * 8;

    int swz = l16 & 7;
    int cA = (quad ^ swz) * 8;             // kc=0 chunk (elem offset in row)
    int cB = ((quad + 4) ^ swz) * 8;       // kc=1

    f32x4 acc[8][3] = {};
    bf16x8 afr[4][2], bfr[3][2];

#define ST1A(KT, HA, BUF) do {                                                  \
    const ushort_t* s_ = Ag + (size_t)(HA) * 128 * G1_K + (KT) * 64;            \
    char* d_ = (char*)&As[BUF][(HA) * 8192] + w * 2048;                         \
    g2l16(s_, d_); g2l16(s_ + 8 * G1_K, d_ + 1024); } while (0)
#define ST1B(KT, G, BUF) do {                                                   \
    const ushort_t* s_ = Bg3 + (size_t)(G) * 64 * G1_K + (KT) * 64;             \
    char* d_ = (char*)&Bs[BUF][(G) * 4096] + w * 1024;                          \
    g2l16(s_, d_); } while (0)

#define RDA1(MH, BUF) do {                                                      \
    const ushort_t* Ar = &As[BUF][(wm_i * 128 + (MH) * 64 + l16) * 64];         \
    _Pragma("unroll") for (int ii = 0; ii < 4; ii++) {                          \
        afr[ii][0] = *(const bf16x8*)(Ar + ii * 1024 + cA);                     \
        afr[ii][1] = *(const bf16x8*)(Ar + ii * 1024 + cB); } } while (0)
#define RDB1(G, BUF) do {                                                       \
    const ushort_t* Br = &Bs[BUF][(wn_i * 48 + (G) * 16 + l16) * 64];           \
    bfr[G][0] = *(const bf16x8*)(Br + cA);                                      \
    bfr[G][1] = *(const bf16x8*)(Br + cB); } while (0)

#define MMA1(MH, G) do {                                                        \
    _Pragma("unroll") for (int kc = 0; kc < 2; kc++)                            \
    _Pragma("unroll") for (int ii = 0; ii < 4; ii++)                            \
        acc[(MH)*4+ii][G] = __builtin_amdgcn_mfma_f32_16x16x32_bf16(            \
            afr[ii][kc], bfr[G][kc], acc[(MH)*4+ii][G], 0, 0, 0); } while (0)

#define BAR1() __builtin_amdgcn_s_barrier()
#define WGK1() do { asm volatile("s_waitcnt lgkmcnt(0)" ::: "memory");          \
                    __builtin_amdgcn_sched_barrier(0); } while (0)

#define TILE1(KT, BUF, OTH) do {                                                \
    /* P1 */                                                                    \
    RDA1(0, BUF); RDB1(0, BUF);                                                 \
    if ((KT) + 1 < G1_NT) ST1A((KT) + 1, 0, OTH);                               \
    BAR1(); WGK1();                                                             \
    __builtin_amdgcn_s_setprio(1); MMA1(0, 0); __builtin_amdgcn_s_setprio(0);   \
    BAR1();                                                                     \
    /* P2 */                                                                    \
    RDB1(1, BUF); RDB1(2, BUF);                                                 \
    if ((KT) + 1 < G1_NT) ST1A((KT) + 1, 1, OTH);                               \
    BAR1(); WGK1();                                                             \
    __builtin_amdgcn_s_setprio(1); MMA1(0, 1); MMA1(0, 2);                      \
    __builtin_amdgcn_s_setprio(0);                                              \
    BAR1();                                                                     \
    /* P3: B reads finished at P2 -> restage B thirds 0,1 into this buf */      \
    RDA1(1, BUF);                                                               \
    if ((KT) + 2 < G1_NT) { ST1B((KT) + 2, 0, BUF); ST1B((KT) + 2, 1, BUF); }   \
    BAR1(); WGK1();                                                             \
    __builtin_amdgcn_s_setprio(1); MMA1(1, 2); MMA1(1, 1);                      \
    __builtin_amdgcn_s_setprio(0);                                              \
    BAR1();                                                                     \
    /* P4: last B third; tile-boundary counted wait */                          \
    if ((KT) + 2 < G1_NT) ST1B((KT) + 2, 2, BUF);                               \
    if ((KT) < G1_NT - 2) asm volatile("s_waitcnt vmcnt(3)" ::: "memory");      \
    else                  asm volatile("s_waitcnt vmcnt(0)" ::: "memory");      \
    BAR1();                                                                     \
    __builtin_amdgcn_sched_barrier(0);                                          \
    __builtin_amdgcn_s_setprio(1); MMA1(1, 0); __builtin_amdgcn_s_setprio(0);   \
    BAR1();                                                                     \
} while (0)

    // prologue: t0.{B,A} -> buf0, t1.B -> buf1 (10 loads/thread);
    // vmcnt(3): t0 fully landed, t1's B thirds in flight.
    ST1B(0, 0, 0); ST1B(0, 1, 0); ST1B(0, 2, 0);
    ST1A(0, 0, 0); ST1A(0, 1, 0);
    ST1B(1, 0, 1); ST1B(1, 1, 1); ST1B(1, 2, 1);
    asm volatile("s_waitcnt vmcnt(3)" ::: "memory");
    BAR1();

    for (int kt = 0; kt < G1_NT; kt += 2) {
        TILE1(kt, 0, 1);
        TILE1(kt + 1, 1, 0);
    }
#undef ST1A
#undef ST1B
#undef RDA1
#undef RDB1
#undef MMA1
#undef BAR1
#undef WGK1
#undef TILE1

    // epilogue: frag (i,j2) -> r = m0+wm_i*128+i*16+quad*4, c = n0+wn_i*48+j2*16+l16
#pragma unroll
    for (int i = 0; i < 8; i++) {
        int r = m0 + wm_i * 128 + i * 16 + quad * 4;
#pragma unroll
        for (int j2 = 0; j2 < 3; j2++) {
            int c = n0 + wn_i * 48 + j2 * 16 + l16;
            float bv_ = bias[c];
            if (c >= 2560) {                          // V cols -> transposed Vt
                ushort4 pack;
                pack.x = f2bf(acc[i][j2][0] + bv_);
                pack.y = f2bf(acc[i][j2][1] + bv_);
                pack.z = f2bf(acc[i][j2][2] + bv_);
                pack.w = f2bf(acc[i][j2][3] + bv_);
                int kv = (c - 2560) >> 7, d = (c - 2560) & 127;
                int b = r >> 11, s0 = r & (S_ - 1);
                *(ushort4*)&Vt[(((size_t)b * KV_ + kv) * HD_ + d) * S_ + s0] = pack;
                continue;
            }
#pragma unroll
            for (int jr = 0; jr < 4; jr++) {
                float v = acc[i][j2][jr] + bv_;
                int s  = (r + jr) & (S_ - 1);
                int dp = (c & 127) >> 1;
                float cs = fc[s * 64 + dp], sn = fs[s * 64 + dp];
                float p = __shfl_xor(v, 1);           // pair element (c^1)
                v = (c & 1) ? (v * cs + p * sn) : (v * cs - p * sn);
                C[(size_t)(r + jr) * NQK + c] = f2bf(v);
            }
        }
    }
}

// ---------------- Flash attention v5: double-buffered staging ----------------

__global__ __launch_bounds__(512, 4) void k_flash(const ushort_t* __restrict__ QK,
                                                  const ushort_t* __restrict__ Vt,
                                                  ushort_t* __restrict__ AO) {
    __shared__ __align__(16) ushort_t Ks[2 * 8192];
    __shared__ __align__(16) ushort_t Vs[2 * 8192];
    __shared__ __align__(16) ushort_t Ps[8 * 16 * 64];
    int h = blockIdx.y, b = blockIdx.z;
    int qt = b ? ((int)gridDim.x - 1 - (int)blockIdx.x) : (int)blockIdx.x;
    int kvh = h >> 2;
    int t = threadIdx.x, w = t >> 6, lane = t & 63, quad = lane >> 4, l16 = lane & 15;
    int qrow0 = qt * 128 + w * 16;
    const float SOFT = 0.08838834764831845f * 1.4426950408889634f; // 1/sqrt(128)*log2(e)

    bf16x8 aq[4];
    {
        const ushort_t* qb = QK + (size_t)(b * S_ + qrow0 + l16) * NQK + h * HD_ + quad * 8;
#pragma unroll
        for (int kc = 0; kc < 4; kc++) aq[kc] = *(const bf16x8*)(qb + kc * 32);
    }
    bf16x8 vone;
#pragma unroll
    for (int i = 0; i < 8; i++) vone[i] = (__bf16)1.0f;

    f32x4 o[8] = {};
    f32x4 ol = {};                 // row-sum accumulator (softmax denominator)
    ushort_t* Psw = Ps + w * 16 * 64;
    int gsw = (l16 >> 1) & 3;      // read-side swizzle bits

    const ushort_t* kgb = QK + (size_t)(b * S_) * NQK + 2048 + kvh * HD_;
    const ushort_t* vgb = Vt + ((size_t)(b * KV_ + kvh) * HD_) * S_;

    int sr, sgs; char *sK0, *sV0;
    if (t < 256) {
        sr = t >> 2; sgs = (t & 3) ^ ((sr >> 1) & 3);
        sK0 = (char*)Ks + (t >> 6) * 1024;
        sV0 = nullptr;
    } else {
        int u = t - 256;
        sr = u >> 2; sgs = (u & 3) ^ ((sr >> 1) & 3);
        sV0 = (char*)Vs + ((t - 256) >> 6) * 1024;
        sK0 = nullptr;
    }

#define STAGE(KT, BUF)                                                          \
    do {                                                                        \
        if (t < 256) {                                                          \
            const ushort_t* kg = kgb + (size_t)((KT) * 64 + sr) * NQK + sgs * 8; \
            char* KsW = sK0 + (BUF) * 16384;                                    \
            _Pragma("unroll")                                                   \
            for (int p = 0; p < 4; p++) g2l16(kg + p * 32, KsW + p * 4096);     \
        } else {                                                                \
            const ushort_t* vg = vgb + (KT) * 64 + sgs * 8 + (size_t)sr * S_;   \
            char* VsW = sV0 + (BUF) * 16384;                                    \
            _Pragma("unroll")                                                   \
            for (int p = 0; p < 4; p++)                                         \
                g2l16(vg + (size_t)((p & 1) * 64) * S_ + (p >> 1) * 32, VsW + p * 4096); \
        }                                                                       \
    } while (0)

    int ktmax = 2 * qt + 1;
    STAGE(0, 0);
    __syncthreads();

    for (int kt = 0; kt <= ktmax; kt++) {
        int cur = kt & 1;
        if (kt < ktmax) STAGE(kt + 1, cur ^ 1);   // prefetch next tile

        if (kt * 64 <= qrow0 + 15) {              // else fully-masked for this wave
            const ushort_t* Kc = Ks + cur * 8192;
            const ushort_t* Vc = Vs + cur * 8192;
            f32x4 sacc[4] = {};
            __builtin_amdgcn_s_setprio(1);        // T5: favor MFMA wave (m191)
#pragma unroll
            for (int kc = 0; kc < 4; kc++)
#pragma unroll
                for (int nb = 0; nb < 4; nb++) {
                    bf16x8 bk = *(const bf16x8*)(Kc + kc * 2048 + (nb * 16 + l16) * 32 + ((quad ^ gsw) * 8));
                    sacc[nb] = __builtin_amdgcn_mfma_f32_16x16x32_bf16(aq[kc], bk, sacc[nb], 0, 0, 0);
                }
            __builtin_amdgcn_s_setprio(0);
            if (kt * 64 + 63 > qrow0) {           // diagonal tile: causal mask
#pragma unroll
                for (int nb = 0; nb < 4; nb++)
#pragma unroll
                    for (int jr = 0; jr < 4; jr++) {
                        int kcol = kt * 64 + nb * 16 + l16;
                        int qr = qrow0 + quad * 4 + jr;
                        if (kcol > qr) sacc[nb][jr] = -1e30f;
                    }
            }
#pragma unroll
            for (int nb = 0; nb < 4; nb++)
#pragma unroll
                for (int jr = 0; jr < 4; jr++)
                    Psw[(quad * 4 + jr) * 64 + nb * 16 + l16] = f2bf(exp2f(sacc[nb][jr] * SOFT));

            asm volatile("s_waitcnt lgkmcnt(0)" ::: "memory");  // P writes -> A-frag reads

            __builtin_amdgcn_s_setprio(1);        // T5: favor MFMA wave (m191)
#pragma unroll
            for (int kc2 = 0; kc2 < 2; kc2++) {
                bf16x8 ap = *(const bf16x8*)(Psw + l16 * 64 + kc2 * 32 + quad * 8);
                ol = __builtin_amdgcn_mfma_f32_16x16x32_bf16(ap, vone, ol, 0, 0, 0);
#pragma unroll
                for (int db = 0; db < 8; db++) {
                    bf16x8 bv = *(const bf16x8*)(Vc + kc2 * 4096 + (db * 16 + l16) * 32 + ((quad ^ gsw) * 8));
                    o[db] = __builtin_amdgcn_mfma_f32_16x16x32_bf16(ap, bv, o[db], 0, 0, 0);
                }
            }
            __builtin_amdgcn_s_setprio(0);
        }
        __syncthreads();   // next tile staged + this tile's LDS reads done
    }
#undef STAGE

    // epilogue: divide by l, write bf16
#pragma unroll
    for (int jr = 0; jr < 4; jr++) {
        float inv = 1.0f / ol[jr];
        size_t rbase = (size_t)(b * S_ + qrow0 + quad * 4 + jr) * D_ + h * HD_;
#pragma unroll
        for (int db = 0; db < 8; db++)
            AO[rbase + db * 16 + l16] = f2bf(o[db][jr] * inv);
    }
}

// ---------------- launch ----------------

extern "C" void kernel_launch(void* const* d_in, const int* in_sizes, int n_in,
                              void* d_out, int out_size, void* d_ws, size_t ws_size,
                              hipStream_t stream) {
    const float* x  = (const float*)d_in[0];
    // d_in[1] = mask (all zeros; reference ignores it — causal built in-kernel)
    const float* fc = (const float*)d_in[2];
    const float* fs = (const float*)d_in[3];
    const float* Wq = (const float*)d_in[4];
    const float* bq = (const float*)d_in[5];
    const float* Wk = (const float*)d_in[6];
    const float* bk = (const float*)d_in[7];
    const float* Wv = (const float*)d_in[8];
    const float* bv = (const float*)d_in[9];
    const float* Wo = (const float*)d_in[10];

    char* ws = (char*)d_ws;
    // layout (bytes); AO aliases xb (xb dead after gemm1). Vt is its own 4 MB
    // (must NOT alias Wt: gemm1 reads Wt while writing Vt). QK stride 2560.
    ushort_t* xb  = (ushort_t*)(ws);                 // 16 MB  (4096x2048 bf16)
    ushort_t* Wt  = (ushort_t*)(ws + 16777216);      // 12 MB  (3072x2048 bf16)
    ushort_t* Wot = (ushort_t*)(ws + 29360128);      //  8 MB  (2048x2048 bf16)
    float*    bb  = (float*)   (ws + 37748736);      // 12 KB
    ushort_t* QK  = (ushort_t*)(ws + 37761024);      // 20 MB  (4096x2560 bf16)
    ushort_t* Vt  = (ushort_t*)(ws + 58732544);      //  4 MB  (2*4*128*2048 bf16)
    ushort_t* AO  = xb;                              // 16 MB  (4096x2048 bf16)
    float* out = (float*)d_out;

    k_prep<<<18444, 256, 0, stream>>>(x, xb, Wq, Wk, Wv, Wo, Wt, Wot, bq, bk, bv, bb);
    k_gemm1_256<<<256, 512, 0, stream>>>(xb, Wt, QK, bb, fc, fs, Vt);
    k_flash<<<dim3(16, 16, 2), 512, 0, stream>>>(QK, Vt, AO);
    k_gemm<128><<<512, 256, 0, stream>>>(AO, Wot, out, nullptr, nullptr, nullptr, nullptr,
                                         4096, 2048, 2048, 0);
}

// Round 6
// 304.242 us; speedup vs baseline: 1.0656x; 1.0050x over previous
//
#include <hip/hip_runtime.h>

// Fused GQA attention block: QKV proj(+RoPE, +V-transpose) -> flash attn -> out proj.
// B=2 S=2048 D=2048 H=16 KV=4 HD=128. All MFMA compute in bf16 (tol = 2% of max).

#define B_  2
#define S_  2048
#define D_  2048
#define H_  16
#define KV_ 4
#define HD_ 128
#define NQK 2560    // QK buffer row stride: 2048 (Q) + 512 (K); V goes to Vt directly

typedef unsigned short ushort_t;
typedef __attribute__((ext_vector_type(8))) __bf16 bf16x8;
typedef __attribute__((ext_vector_type(4))) float  f32x4;

__device__ __forceinline__ ushort_t f2bf(float f) {
    unsigned u = __float_as_uint(f);
    u += 0x7FFFu + ((u >> 16) & 1u);          // round-to-nearest-even
    return (ushort_t)(u >> 16);
}
// compiler-native cast (emits v_cvt_pk_bf16_f32, RNE) — 1 op vs 4 for f2bf
__device__ __forceinline__ ushort_t f2bf_fast(float f) {
    __bf16 h = (__bf16)f;
    return *(ushort_t*)&h;
}
__device__ __forceinline__ float bf2f(ushort_t h) {
    return __uint_as_float(((unsigned)h) << 16);
}

// async global->LDS, 16B per lane; LDS dest = wave-uniform base + lane*16
__device__ __forceinline__ void g2l16(const void* g, void* l) {
    __builtin_amdgcn_global_load_lds(
        (const __attribute__((address_space(1))) unsigned int*)g,
        (__attribute__((address_space(3))) unsigned int*)l, 16, 0, 0);
}

// softmax scale 1/sqrt(128)*log2(e), folded into gemm1's Q epilogue (r6)
#define SOFTSC 0.12751743f

// ---------------- fused prep: x->bf16, 4 weight transposes, bias pack -------

__global__ __launch_bounds__(256) void k_prep(
    const float* __restrict__ x,  ushort_t* __restrict__ xb,
    const float* __restrict__ Wq, const float* __restrict__ Wk,
    const float* __restrict__ Wv, const float* __restrict__ Wo,
    ushort_t* __restrict__ Wt, ushort_t* __restrict__ Wot,
    const float* __restrict__ bq, const float* __restrict__ bk,
    const float* __restrict__ bv, float* __restrict__ bb) {
    __shared__ float tile[32][33];
    int id = blockIdx.x, t = threadIdx.x;
    if (id < 8192) {                                   // x fp32 -> bf16
        int i = id * 256 + t;
        float4 v = ((const float4*)x)[i];
        ushort4 o;
        o.x = f2bf(v.x); o.y = f2bf(v.y); o.z = f2bf(v.z); o.w = f2bf(v.w);
        ((ushort4*)xb)[i] = o;
        return;
    }
    const float* src; ushort_t* dst; int C, bid;
    if (id < 12288)      { src = Wq; dst = Wt;                       C = 2048; bid = id - 8192;  }
    else if (id < 13312) { src = Wk; dst = Wt + (size_t)2048 * 2048; C = 512;  bid = id - 12288; }
    else if (id < 14336) { src = Wv; dst = Wt + (size_t)2560 * 2048; C = 512;  bid = id - 13312; }
    else if (id < 18432) { src = Wo; dst = Wot;                      C = 2048; bid = id - 14336; }
    else {                                             // bias pack
        int i = (id - 18432) * 256 + t;
        if (i < 3072)
            bb[i] = (i < 2048) ? bq[i] : (i < 2560) ? bk[i - 2048] : bv[i - 2560];
        return;
    }
    const int R = 2048;
    int nbc = C >> 5;
    int c0 = (bid % nbc) * 32, r0 = (bid / nbc) * 32;
    int tx = t & 31, ty = t >> 5;
    for (int i = ty; i < 32; i += 8)
        tile[i][tx] = src[(size_t)(r0 + i) * C + c0 + tx];
    __syncthreads();
    for (int i = ty; i < 32; i += 8)
        dst[(size_t)(c0 + i) * R + r0 + tx] = f2bf(tile[tx][i]);
}

// ---------------- gemm2: 128x128 tile, 2-phase (unchanged, out proj only) ---

template<int BK>
__global__ __launch_bounds__(256, 3) void k_gemm(const ushort_t* __restrict__ A,
                                                 const ushort_t* __restrict__ Bt,
                                                 void* __restrict__ Cp,
                                                 const float* __restrict__ bias,
                                                 const float* __restrict__ fc,
                                                 const float* __restrict__ fs,
                                                 ushort_t* __restrict__ Vt,
                                                 int M, int N, int K, int out_bf16) {
    constexpr int GPR    = BK / 8;    // 16B granules per row
    constexpr int RPR    = 64 / GPR;  // rows staged per round per wave
    constexpr int ROUNDS = 32 / RPR;  // rounds to cover 32 rows per wave
    __shared__ __align__(16) ushort_t As[128 * BK];
    __shared__ __align__(16) ushort_t Bs[128 * BK];
    int t = threadIdx.x;
    int w = t >> 6, lane = t & 63, quad = lane >> 4, l16 = lane & 15;
    int L = blockIdx.x;
    int mper = (M >> 7) >> 3;                 // m-tiles per XCD
    int xcd = L & 7, j = L >> 3;
    int m0 = (xcd * mper + (j % mper)) * 128;
    int n0 = (j / mper) * 128;
    int wm = (w >> 1) * 64, wn = (w & 1) * 64;
    f32x4 acc[4][4] = {};

    int rlo = lane / GPR;                     // row-within-round
    int gsl = lane & (GPR - 1);               // slot granule
    const ushort_t* Ag = A  + (size_t)(m0 + w * 32) * K;
    const ushort_t* Bg = Bt + (size_t)(n0 + w * 32) * K;
    int rsw = (l16 & 7);                      // read-side swizzle bits

    for (int k0 = 0; k0 < K; k0 += BK) {
        __syncthreads();
#pragma unroll
        for (int p = 0; p < ROUNDS; p++) {
            int row = p * RPR + rlo;
            int gs = gsl ^ (row & 7);
            g2l16(Ag + (size_t)row * K + k0 + gs * 8, (char*)As + (w * 32 + p * RPR) * 2 * BK);
            g2l16(Bg + (size_t)row * K + k0 + gs * 8, (char*)Bs + (w * 32 + p * RPR) * 2 * BK);
        }
        __syncthreads();
#pragma unroll
        for (int kc = 0; kc < BK / 32; kc++) {
            int gg = quad + kc * 4;
            bf16x8 af[4], bfr[4];
#pragma unroll
            for (int i = 0; i < 4; i++)
                af[i] = *(const bf16x8*)(As + (wm + i * 16 + l16) * BK + ((gg ^ rsw) * 8));
#pragma unroll
            for (int j2 = 0; j2 < 4; j2++)
                bfr[j2] = *(const bf16x8*)(Bs + (wn + j2 * 16 + l16) * BK + ((gg ^ rsw) * 8));
#pragma unroll
            for (int i = 0; i < 4; i++)
#pragma unroll
                for (int j2 = 0; j2 < 4; j2++)
                    acc[i][j2] = __builtin_amdgcn_mfma_f32_16x16x32_bf16(af[i], bfr[j2], acc[i][j2], 0, 0, 0);
        }
    }
    int ostride = fc ? NQK : N;
#pragma unroll
    for (int i = 0; i < 4; i++) {
        int r = m0 + wm + i * 16 + quad * 4;
#pragma unroll
        for (int j2 = 0; j2 < 4; j2++) {
            int c = n0 + wn + j2 * 16 + l16;
            float bv_ = bias ? bias[c] : 0.f;
            if (fc && c >= 2560) {
                ushort4 pack;
                pack.x = f2bf(acc[i][j2][0] + bv_);
                pack.y = f2bf(acc[i][j2][1] + bv_);
                pack.z = f2bf(acc[i][j2][2] + bv_);
                pack.w = f2bf(acc[i][j2][3] + bv_);
                int kv = (c - 2560) >> 7, d = (c - 2560) & 127;
                int b = r >> 11, s0 = r & (S_ - 1);
                *(ushort4*)&Vt[(((size_t)b * KV_ + kv) * HD_ + d) * S_ + s0] = pack;
                continue;
            }
#pragma unroll
            for (int jr = 0; jr < 4; jr++) {
                float v = acc[i][j2][jr] + bv_;
                if (fc) {
                    int s  = (r + jr) & (S_ - 1);
                    int dp = (c & 127) >> 1;
                    float cs = fc[s * 64 + dp], sn = fs[s * 64 + dp];
                    float p = __shfl_xor(v, 1);
                    v = (c & 1) ? (v * cs + p * sn) : (v * cs - p * sn);
                }
                if (out_bf16) ((ushort_t*)Cp)[(size_t)(r + jr) * ostride + c] = f2bf(v);
                else          ((float*)Cp)[(size_t)(r + jr) * ostride + c] = v;
            }
        }
    }
}

// ---------------- gemm1: 256x192 8-phase counted-vmcnt, v3 ------------------
// (r4: grid 256 = exact machine fill; see r4 notes.) r6 delta: Q columns
// (c<2048) are pre-scaled by SOFTSC in f32 before bf16 rounding -- removes
// 16 v_mul/tile-step from k_flash's softmax at zero cost here.

#define G1_K  2048
#define G1_NT 32

__global__ __launch_bounds__(512, 2) void k_gemm1_256(
    const ushort_t* __restrict__ A, const ushort_t* __restrict__ Bt,
    ushort_t* __restrict__ C, const float* __restrict__ bias,
    const float* __restrict__ fc, const float* __restrict__ fs,
    ushort_t* __restrict__ Vt) {
    __shared__ __align__(16) ushort_t As[2][16384];   // 2 bufs x 256 rows x 64
    __shared__ __align__(16) ushort_t Bs[2][12288];   // 2 bufs x 192 rows x 64
    int t = threadIdx.x;
    int w = t >> 6, lane = t & 63, quad = lane >> 4, l16 = lane & 15;
    int wm_i = w >> 2, wn_i = w & 3;

    int L = blockIdx.x;                    // 16 mt x 16 nt, m striped per XCD
    int xcd = L & 7, j = L >> 3;           // mper = 16/8 = 2
    int m0 = (xcd * 2 + (j & 1)) * 256;
    int n0 = (j >> 1) * 192;

    int srow = w * 16 + (lane >> 3);
    int sg   = (lane & 7) ^ (lane >> 3);
    const ushort_t* Ag  = A  + (size_t)(m0 + srow) * G1_K + sg * 8;
    const ushort_t* Bg3 = Bt + (size_t)(n0 + w * 8 + (lane >> 3)) * G1_K + sg * 8;

    int swz = l16 & 7;
    int cA = (quad ^ swz) * 8;             // kc=0 chunk (elem offset in row)
    int cB = ((quad + 4) ^ swz) * 8;       // kc=1

    f32x4 acc[8][3] = {};
    bf16x8 afr[4][2], bfr[3][2];

#define ST1A(KT, HA, BUF) do {                                                  \
    const ushort_t* s_ = Ag + (size_t)(HA) * 128 * G1_K + (KT) * 64;            \
    char* d_ = (char*)&As[BUF][(HA) * 8192] + w * 2048;                         \
    g2l16(s_, d_); g2l16(s_ + 8 * G1_K, d_ + 1024); } while (0)
#define ST1B(KT, G, BUF) do {                                                   \
    const ushort_t* s_ = Bg3 + (size_t)(G) * 64 * G1_K + (KT) * 64;             \
    char* d_ = (char*)&Bs[BUF][(G) * 4096] + w * 1024;                          \
    g2l16(s_, d_); } while (0)

#define RDA1(MH, BUF) do {                                                      \
    const ushort_t* Ar = &As[BUF][(wm_i * 128 + (MH) * 64 + l16) * 64];         \
    _Pragma("unroll") for (int ii = 0; ii < 4; ii++) {                          \
        afr[ii][0] = *(const bf16x8*)(Ar + ii * 1024 + cA);                     \
        afr[ii][1] = *(const bf16x8*)(Ar + ii * 1024 + cB); } } while (0)
#define RDB1(G, BUF) do {                                                       \
    const ushort_t* Br = &Bs[BUF][(wn_i * 48 + (G) * 16 + l16) * 64];           \
    bfr[G][0] = *(const bf16x8*)(Br + cA);                                      \
    bfr[G][1] = *(const bf16x8*)(Br + cB); } while (0)

#define MMA1(MH, G) do {                                                        \
    _Pragma("unroll") for (int kc = 0; kc < 2; kc++)                            \
    _Pragma("unroll") for (int ii = 0; ii < 4; ii++)                            \
        acc[(MH)*4+ii][G] = __builtin_amdgcn_mfma_f32_16x16x32_bf16(            \
            afr[ii][kc], bfr[G][kc], acc[(MH)*4+ii][G], 0, 0, 0); } while (0)

#define BAR1() __builtin_amdgcn_s_barrier()
#define WGK1() do { asm volatile("s_waitcnt lgkmcnt(0)" ::: "memory");          \
                    __builtin_amdgcn_sched_barrier(0); } while (0)

#define TILE1(KT, BUF, OTH) do {                                                \
    /* P1 */                                                                    \
    RDA1(0, BUF); RDB1(0, BUF);                                                 \
    if ((KT) + 1 < G1_NT) ST1A((KT) + 1, 0, OTH);                               \
    BAR1(); WGK1();                                                             \
    __builtin_amdgcn_s_setprio(1); MMA1(0, 0); __builtin_amdgcn_s_setprio(0);   \
    BAR1();                                                                     \
    /* P2 */                                                                    \
    RDB1(1, BUF); RDB1(2, BUF);                                                 \
    if ((KT) + 1 < G1_NT) ST1A((KT) + 1, 1, OTH);                               \
    BAR1(); WGK1();                                                             \
    __builtin_amdgcn_s_setprio(1); MMA1(0, 1); MMA1(0, 2);                      \
    __builtin_amdgcn_s_setprio(0);                                              \
    BAR1();                                                                     \
    /* P3: B reads finished at P2 -> restage B thirds 0,1 into this buf */      \
    RDA1(1, BUF);                                                               \
    if ((KT) + 2 < G1_NT) { ST1B((KT) + 2, 0, BUF); ST1B((KT) + 2, 1, BUF); }   \
    BAR1(); WGK1();                                                             \
    __builtin_amdgcn_s_setprio(1); MMA1(1, 2); MMA1(1, 1);                      \
    __builtin_amdgcn_s_setprio(0);                                              \
    BAR1();                                                                     \
    /* P4: last B third; tile-boundary counted wait */                          \
    if ((KT) + 2 < G1_NT) ST1B((KT) + 2, 2, BUF);                               \
    if ((KT) < G1_NT - 2) asm volatile("s_waitcnt vmcnt(3)" ::: "memory");      \
    else                  asm volatile("s_waitcnt vmcnt(0)" ::: "memory");      \
    BAR1();                                                                     \
    __builtin_amdgcn_sched_barrier(0);                                          \
    __builtin_amdgcn_s_setprio(1); MMA1(1, 0); __builtin_amdgcn_s_setprio(0);   \
    BAR1();                                                                     \
} while (0)

    // prologue: t0.{B,A} -> buf0, t1.B -> buf1 (10 loads/thread);
    // vmcnt(3): t0 fully landed, t1's B thirds in flight.
    ST1B(0, 0, 0); ST1B(0, 1, 0); ST1B(0, 2, 0);
    ST1A(0, 0, 0); ST1A(0, 1, 0);
    ST1B(1, 0, 1); ST1B(1, 1, 1); ST1B(1, 2, 1);
    asm volatile("s_waitcnt vmcnt(3)" ::: "memory");
    BAR1();

    for (int kt = 0; kt < G1_NT; kt += 2) {
        TILE1(kt, 0, 1);
        TILE1(kt + 1, 1, 0);
    }
#undef ST1A
#undef ST1B
#undef RDA1
#undef RDB1
#undef MMA1
#undef BAR1
#undef WGK1
#undef TILE1

    // epilogue: frag (i,j2) -> r = m0+wm_i*128+i*16+quad*4, c = n0+wn_i*48+j2*16+l16
#pragma unroll
    for (int i = 0; i < 8; i++) {
        int r = m0 + wm_i * 128 + i * 16 + quad * 4;
#pragma unroll
        for (int j2 = 0; j2 < 3; j2++) {
            int c = n0 + wn_i * 48 + j2 * 16 + l16;
            float bv_ = bias[c];
            if (c >= 2560) {                          // V cols -> transposed Vt
                ushort4 pack;
                pack.x = f2bf(acc[i][j2][0] + bv_);
                pack.y = f2bf(acc[i][j2][1] + bv_);
                pack.z = f2bf(acc[i][j2][2] + bv_);
                pack.w = f2bf(acc[i][j2][3] + bv_);
                int kv = (c - 2560) >> 7, d = (c - 2560) & 127;
                int b = r >> 11, s0 = r & (S_ - 1);
                *(ushort4*)&Vt[(((size_t)b * KV_ + kv) * HD_ + d) * S_ + s0] = pack;
                continue;
            }
#pragma unroll
            for (int jr = 0; jr < 4; jr++) {
                float v = acc[i][j2][jr] + bv_;
                int s  = (r + jr) & (S_ - 1);
                int dp = (c & 127) >> 1;
                float cs = fc[s * 64 + dp], sn = fs[s * 64 + dp];
                float p = __shfl_xor(v, 1);           // pair element (c^1)
                v = (c & 1) ? (v * cs + p * sn) : (v * cs - p * sn);
                if (c < 2048) v *= SOFTSC;            // fold softmax scale into Q
                C[(size_t)(r + jr) * NQK + c] = f2bf(v);
            }
        }
    }
}

// ---------------- Flash attention v6: P-LDS swizzle + lean softmax ----------
// r6 deltas vs v5 (counters: 3.78M bank-conflict cycles = 9% of CU-cycles,
// VALUBusy 37.6 > MfmaUtil 22):
//  (1) P buffer XOR-swizzle (T2): 16B-granule slot s of row q holds granule
//      s^(q&7). PV A-frag ds_read_b128 goes 4->8 bank-groups/phase
//      (conflict-free); P writes 4-way -> 2-way (free).
//  (2) softmax scale folded into gemm1's Q output -> exp2f(sacc) direct.
//  (3) P-write conversion via native (__bf16) cast (v_cvt_pk_bf16_f32).

__global__ __launch_bounds__(512, 4) void k_flash(const ushort_t* __restrict__ QK,
                                                  const ushort_t* __restrict__ Vt,
                                                  ushort_t* __restrict__ AO) {
    __shared__ __align__(16) ushort_t Ks[2 * 8192];
    __shared__ __align__(16) ushort_t Vs[2 * 8192];
    __shared__ __align__(16) ushort_t Ps[8 * 16 * 64];
    int h = blockIdx.y, b = blockIdx.z;
    int qt = b ? ((int)gridDim.x - 1 - (int)blockIdx.x) : (int)blockIdx.x;
    int kvh = h >> 2;
    int t = threadIdx.x, w = t >> 6, lane = t & 63, quad = lane >> 4, l16 = lane & 15;
    int qrow0 = qt * 128 + w * 16;

    bf16x8 aq[4];
    {
        const ushort_t* qb = QK + (size_t)(b * S_ + qrow0 + l16) * NQK + h * HD_ + quad * 8;
#pragma unroll
        for (int kc = 0; kc < 4; kc++) aq[kc] = *(const bf16x8*)(qb + kc * 32);
    }
    bf16x8 vone;
#pragma unroll
    for (int i = 0; i < 8; i++) vone[i] = (__bf16)1.0f;

    f32x4 o[8] = {};
    f32x4 ol = {};                 // row-sum accumulator (softmax denominator)
    ushort_t* Psw = Ps + w * 16 * 64;
    int gsw = (l16 >> 1) & 3;      // K/V read-side swizzle bits

    const ushort_t* kgb = QK + (size_t)(b * S_) * NQK + 2048 + kvh * HD_;
    const ushort_t* vgb = Vt + ((size_t)(b * KV_ + kvh) * HD_) * S_;

    int sr, sgs; char *sK0, *sV0;
    if (t < 256) {
        sr = t >> 2; sgs = (t & 3) ^ ((sr >> 1) & 3);
        sK0 = (char*)Ks + (t >> 6) * 1024;
        sV0 = nullptr;
    } else {
        int u = t - 256;
        sr = u >> 2; sgs = (u & 3) ^ ((sr >> 1) & 3);
        sV0 = (char*)Vs + ((t - 256) >> 6) * 1024;
        sK0 = nullptr;
    }

#define STAGE(KT, BUF)                                                          \
    do {                                                                        \
        if (t < 256) {                                                          \
            const ushort_t* kg = kgb + (size_t)((KT) * 64 + sr) * NQK + sgs * 8; \
            char* KsW = sK0 + (BUF) * 16384;                                    \
            _Pragma("unroll")                                                   \
            for (int p = 0; p < 4; p++) g2l16(kg + p * 32, KsW + p * 4096);     \
        } else {                                                                \
            const ushort_t* vg = vgb + (KT) * 64 + sgs * 8 + (size_t)sr * S_;   \
            char* VsW = sV0 + (BUF) * 16384;                                    \
            _Pragma("unroll")                                                   \
            for (int p = 0; p < 4; p++)                                         \
                g2l16(vg + (size_t)((p & 1) * 64) * S_ + (p >> 1) * 32, VsW + p * 4096); \
        }                                                                       \
    } while (0)

    int ktmax = 2 * qt + 1;
    STAGE(0, 0);
    __syncthreads();

    for (int kt = 0; kt <= ktmax; kt++) {
        int cur = kt & 1;
        if (kt < ktmax) STAGE(kt + 1, cur ^ 1);   // prefetch next tile

        if (kt * 64 <= qrow0 + 15) {              // else fully-masked for this wave
            const ushort_t* Kc = Ks + cur * 8192;
            const ushort_t* Vc = Vs + cur * 8192;
            f32x4 sacc[4] = {};
            __builtin_amdgcn_s_setprio(1);        // T5: favor MFMA wave (m191)
#pragma unroll
            for (int kc = 0; kc < 4; kc++)
#pragma unroll
                for (int nb = 0; nb < 4; nb++) {
                    bf16x8 bk = *(const bf16x8*)(Kc + kc * 2048 + (nb * 16 + l16) * 32 + ((quad ^ gsw) * 8));
                    sacc[nb] = __builtin_amdgcn_mfma_f32_16x16x32_bf16(aq[kc], bk, sacc[nb], 0, 0, 0);
                }
            __builtin_amdgcn_s_setprio(0);
            if (kt * 64 + 63 > qrow0) {           // diagonal tile: causal mask
#pragma unroll
                for (int nb = 0; nb < 4; nb++)
#pragma unroll
                    for (int jr = 0; jr < 4; jr++) {
                        int kcol = kt * 64 + nb * 16 + l16;
                        int qr = qrow0 + quad * 4 + jr;
                        if (kcol > qr) sacc[nb][jr] = -1e30f;
                    }
            }
            // P write, granule-swizzled: slot (key>>3)^(q&7) of row q
#pragma unroll
            for (int nb = 0; nb < 4; nb++)
#pragma unroll
                for (int jr = 0; jr < 4; jr++) {
                    int q  = quad * 4 + jr;
                    int gi = (nb * 2 + (l16 >> 3)) ^ (q & 7);
                    Psw[q * 64 + gi * 8 + (l16 & 7)] = f2bf_fast(exp2f(sacc[nb][jr]));
                }

            asm volatile("s_waitcnt lgkmcnt(0)" ::: "memory");  // P writes -> A-frag reads

            __builtin_amdgcn_s_setprio(1);        // T5: favor MFMA wave (m191)
#pragma unroll
            for (int kc2 = 0; kc2 < 2; kc2++) {
                bf16x8 ap = *(const bf16x8*)(Psw + l16 * 64 + (((kc2 * 4 + quad) ^ (l16 & 7)) * 8));
                ol = __builtin_amdgcn_mfma_f32_16x16x32_bf16(ap, vone, ol, 0, 0, 0);
#pragma unroll
                for (int db = 0; db < 8; db++) {
                    bf16x8 bv = *(const bf16x8*)(Vc + kc2 * 4096 + (db * 16 + l16) * 32 + ((quad ^ gsw) * 8));
                    o[db] = __builtin_amdgcn_mfma_f32_16x16x32_bf16(ap, bv, o[db], 0, 0, 0);
                }
            }
            __builtin_amdgcn_s_setprio(0);
        }
        __syncthreads();   // next tile staged + this tile's LDS reads done
    }
#undef STAGE

    // epilogue: divide by l, write bf16
#pragma unroll
    for (int jr = 0; jr < 4; jr++) {
        float inv = 1.0f / ol[jr];
        size_t rbase = (size_t)(b * S_ + qrow0 + quad * 4 + jr) * D_ + h * HD_;
#pragma unroll
        for (int db = 0; db < 8; db++)
            AO[rbase + db * 16 + l16] = f2bf(o[db][jr] * inv);
    }
}

// ---------------- launch ----------------

extern "C" void kernel_launch(void* const* d_in, const int* in_sizes, int n_in,
                              void* d_out, int out_size, void* d_ws, size_t ws_size,
                              hipStream_t stream) {
    const float* x  = (const float*)d_in[0];
    // d_in[1] = mask (all zeros; reference ignores it — causal built in-kernel)
    const float* fc = (const float*)d_in[2];
    const float* fs = (const float*)d_in[3];
    const float* Wq = (const float*)d_in[4];
    const float* bq = (const float*)d_in[5];
    const float* Wk = (const float*)d_in[6];
    const float* bk = (const float*)d_in[7];
    const float* Wv = (const float*)d_in[8];
    const float* bv = (const float*)d_in[9];
    const float* Wo = (const float*)d_in[10];

    char* ws = (char*)d_ws;
    // layout (bytes); AO aliases xb (xb dead after gemm1). Vt is its own 4 MB
    // (must NOT alias Wt: gemm1 reads Wt while writing Vt). QK stride 2560.
    ushort_t* xb  = (ushort_t*)(ws);                 // 16 MB  (4096x2048 bf16)
    ushort_t* Wt  = (ushort_t*)(ws + 16777216);      // 12 MB  (3072x2048 bf16)
    ushort_t* Wot = (ushort_t*)(ws + 29360128);      //  8 MB  (2048x2048 bf16)
    float*    bb  = (float*)   (ws + 37748736);      // 12 KB
    ushort_t* QK  = (ushort_t*)(ws + 37761024);      // 20 MB  (4096x2560 bf16)
    ushort_t* Vt  = (ushort_t*)(ws + 58732544);      //  4 MB  (2*4*128*2048 bf16)
    ushort_t* AO  = xb;                              // 16 MB  (4096x2048 bf16)
    float* out = (float*)d_out;

    k_prep<<<18444, 256, 0, stream>>>(x, xb, Wq, Wk, Wv, Wo, Wt, Wot, bq, bk, bv, bb);
    k_gemm1_256<<<256, 512, 0, stream>>>(xb, Wt, QK, bb, fc, fs, Vt);
    k_flash<<<dim3(16, 16, 2), 512, 0, stream>>>(QK, Vt, AO);
    k_gemm<128><<<512, 256, 0, stream>>>(AO, Wot, out, nullptr, nullptr, nullptr, nullptr,
                                         4096, 2048, 2048, 0);
}

// Round 7
// 303.575 us; speedup vs baseline: 1.0680x; 1.0022x over previous
//
#include <hip/hip_runtime.h>

// Fused GQA attention block: QKV proj(+RoPE, +V-transpose) -> flash attn -> out proj.
// B=2 S=2048 D=2048 H=16 KV=4 HD=128. All MFMA compute in bf16 (tol = 2% of max).

#define B_  2
#define S_  2048
#define D_  2048
#define H_  16
#define KV_ 4
#define HD_ 128
#define NQK 2560    // QK buffer row stride: 2048 (Q) + 512 (K); V goes to Vt directly

typedef unsigned short ushort_t;
typedef __attribute__((ext_vector_type(8))) __bf16 bf16x8;
typedef __attribute__((ext_vector_type(4))) float  f32x4;

__device__ __forceinline__ ushort_t f2bf(float f) {
    unsigned u = __float_as_uint(f);
    u += 0x7FFFu + ((u >> 16) & 1u);          // round-to-nearest-even
    return (ushort_t)(u >> 16);
}
// compiler-native cast (emits v_cvt_pk_bf16_f32, RNE) — 1 op vs 4 for f2bf
__device__ __forceinline__ ushort_t f2bf_fast(float f) {
    __bf16 h = (__bf16)f;
    return *(ushort_t*)&h;
}
__device__ __forceinline__ float bf2f(ushort_t h) {
    return __uint_as_float(((unsigned)h) << 16);
}

// async global->LDS, 16B per lane; LDS dest = wave-uniform base + lane*16
__device__ __forceinline__ void g2l16(const void* g, void* l) {
    __builtin_amdgcn_global_load_lds(
        (const __attribute__((address_space(1))) unsigned int*)g,
        (__attribute__((address_space(3))) unsigned int*)l, 16, 0, 0);
}

// softmax scale 1/sqrt(128)*log2(e), folded into gemm1's Q epilogue (r6)
#define SOFTSC 0.12751743f

// ---------------- fused prep: x->bf16, 4 weight transposes, bias pack -------

__global__ __launch_bounds__(256) void k_prep(
    const float* __restrict__ x,  ushort_t* __restrict__ xb,
    const float* __restrict__ Wq, const float* __restrict__ Wk,
    const float* __restrict__ Wv, const float* __restrict__ Wo,
    ushort_t* __restrict__ Wt, ushort_t* __restrict__ Wot,
    const float* __restrict__ bq, const float* __restrict__ bk,
    const float* __restrict__ bv, float* __restrict__ bb) {
    __shared__ float tile[32][33];
    int id = blockIdx.x, t = threadIdx.x;
    if (id < 8192) {                                   // x fp32 -> bf16
        int i = id * 256 + t;
        float4 v = ((const float4*)x)[i];
        ushort4 o;
        o.x = f2bf(v.x); o.y = f2bf(v.y); o.z = f2bf(v.z); o.w = f2bf(v.w);
        ((ushort4*)xb)[i] = o;
        return;
    }
    const float* src; ushort_t* dst; int C, bid;
    if (id < 12288)      { src = Wq; dst = Wt;                       C = 2048; bid = id - 8192;  }
    else if (id < 13312) { src = Wk; dst = Wt + (size_t)2048 * 2048; C = 512;  bid = id - 12288; }
    else if (id < 14336) { src = Wv; dst = Wt + (size_t)2560 * 2048; C = 512;  bid = id - 13312; }
    else if (id < 18432) { src = Wo; dst = Wot;                      C = 2048; bid = id - 14336; }
    else {                                             // bias pack
        int i = (id - 18432) * 256 + t;
        if (i < 3072)
            bb[i] = (i < 2048) ? bq[i] : (i < 2560) ? bk[i - 2048] : bv[i - 2560];
        return;
    }
    const int R = 2048;
    int nbc = C >> 5;
    int c0 = (bid % nbc) * 32, r0 = (bid / nbc) * 32;
    int tx = t & 31, ty = t >> 5;
    for (int i = ty; i < 32; i += 8)
        tile[i][tx] = src[(size_t)(r0 + i) * C + c0 + tx];
    __syncthreads();
    for (int i = ty; i < 32; i += 8)
        dst[(size_t)(c0 + i) * R + r0 + tx] = f2bf(tile[tx][i]);
}

// ---------------- gemm2: 128x128 tile, 2-phase (unchanged, out proj only) ---

template<int BK>
__global__ __launch_bounds__(256, 3) void k_gemm(const ushort_t* __restrict__ A,
                                                 const ushort_t* __restrict__ Bt,
                                                 void* __restrict__ Cp,
                                                 const float* __restrict__ bias,
                                                 const float* __restrict__ fc,
                                                 const float* __restrict__ fs,
                                                 ushort_t* __restrict__ Vt,
                                                 int M, int N, int K, int out_bf16) {
    constexpr int GPR    = BK / 8;    // 16B granules per row
    constexpr int RPR    = 64 / GPR;  // rows staged per round per wave
    constexpr int ROUNDS = 32 / RPR;  // rounds to cover 32 rows per wave
    __shared__ __align__(16) ushort_t As[128 * BK];
    __shared__ __align__(16) ushort_t Bs[128 * BK];
    int t = threadIdx.x;
    int w = t >> 6, lane = t & 63, quad = lane >> 4, l16 = lane & 15;
    int L = blockIdx.x;
    int mper = (M >> 7) >> 3;                 // m-tiles per XCD
    int xcd = L & 7, j = L >> 3;
    int m0 = (xcd * mper + (j % mper)) * 128;
    int n0 = (j / mper) * 128;
    int wm = (w >> 1) * 64, wn = (w & 1) * 64;
    f32x4 acc[4][4] = {};

    int rlo = lane / GPR;                     // row-within-round
    int gsl = lane & (GPR - 1);               // slot granule
    const ushort_t* Ag = A  + (size_t)(m0 + w * 32) * K;
    const ushort_t* Bg = Bt + (size_t)(n0 + w * 32) * K;
    int rsw = (l16 & 7);                      // read-side swizzle bits

    for (int k0 = 0; k0 < K; k0 += BK) {
        __syncthreads();
#pragma unroll
        for (int p = 0; p < ROUNDS; p++) {
            int row = p * RPR + rlo;
            int gs = gsl ^ (row & 7);
            g2l16(Ag + (size_t)row * K + k0 + gs * 8, (char*)As + (w * 32 + p * RPR) * 2 * BK);
            g2l16(Bg + (size_t)row * K + k0 + gs * 8, (char*)Bs + (w * 32 + p * RPR) * 2 * BK);
        }
        __syncthreads();
#pragma unroll
        for (int kc = 0; kc < BK / 32; kc++) {
            int gg = quad + kc * 4;
            bf16x8 af[4], bfr[4];
#pragma unroll
            for (int i = 0; i < 4; i++)
                af[i] = *(const bf16x8*)(As + (wm + i * 16 + l16) * BK + ((gg ^ rsw) * 8));
#pragma unroll
            for (int j2 = 0; j2 < 4; j2++)
                bfr[j2] = *(const bf16x8*)(Bs + (wn + j2 * 16 + l16) * BK + ((gg ^ rsw) * 8));
#pragma unroll
            for (int i = 0; i < 4; i++)
#pragma unroll
                for (int j2 = 0; j2 < 4; j2++)
                    acc[i][j2] = __builtin_amdgcn_mfma_f32_16x16x32_bf16(af[i], bfr[j2], acc[i][j2], 0, 0, 0);
        }
    }
    int ostride = fc ? NQK : N;
#pragma unroll
    for (int i = 0; i < 4; i++) {
        int r = m0 + wm + i * 16 + quad * 4;
#pragma unroll
        for (int j2 = 0; j2 < 4; j2++) {
            int c = n0 + wn + j2 * 16 + l16;
            float bv_ = bias ? bias[c] : 0.f;
            if (fc && c >= 2560) {
                ushort4 pack;
                pack.x = f2bf(acc[i][j2][0] + bv_);
                pack.y = f2bf(acc[i][j2][1] + bv_);
                pack.z = f2bf(acc[i][j2][2] + bv_);
                pack.w = f2bf(acc[i][j2][3] + bv_);
                int kv = (c - 2560) >> 7, d = (c - 2560) & 127;
                int b = r >> 11, s0 = r & (S_ - 1);
                *(ushort4*)&Vt[(((size_t)b * KV_ + kv) * HD_ + d) * S_ + s0] = pack;
                continue;
            }
#pragma unroll
            for (int jr = 0; jr < 4; jr++) {
                float v = acc[i][j2][jr] + bv_;
                if (fc) {
                    int s  = (r + jr) & (S_ - 1);
                    int dp = (c & 127) >> 1;
                    float cs = fc[s * 64 + dp], sn = fs[s * 64 + dp];
                    float p = __shfl_xor(v, 1);
                    v = (c & 1) ? (v * cs + p * sn) : (v * cs - p * sn);
                }
                if (out_bf16) ((ushort_t*)Cp)[(size_t)(r + jr) * ostride + c] = f2bf(v);
                else          ((float*)Cp)[(size_t)(r + jr) * ostride + c] = v;
            }
        }
    }
}

// ---------------- gemm1: 256x192, register-pipelined counted-lgkm, v4 -------
// r7 post-mortem of v3 (67us, MfmaUtil 30%): per-tile per-CU arithmetic says
// MFMA floor 1548cyc ~ LDS-read traffic 1408cyc, but v3's phase structure
// {reads; BAR; lgkm(0); MFMA; BAR} SERIALIZES the LDS and MFMA pipes. v4
// overlaps them in-wave: fragment reads are issued one phase EARLY, and each
// phase waits lgkmcnt(N_just_issued) -- draining exactly the previous phase's
// reads while this phase's stay in flight under the MFMA (counted-lgkm = the
// lgkm analog of T4). Barriers cut 8->4 per tile.
//   read schedule: S@P4prev={afr0(M0),bfr0(g0)} 10rd | S@P1={bfr1,bfr2} 4rd |
//                  S@P2={afr1(M1)} 8rd | S@P3=empty
//   phase p: [stage_p; (P4: vmcnt(3)); BAR; issue S_p; lgkm(4/8/0/-);
//             setprio1; MFMA_p; setprio0]
//   MFMA: P1=(M0,g0) 8, P2=(M0,g1)+(M0,g2) 16, P3=(M1,g2)+(M1,g1) 16,
//         P4=(M1,g0) 8   (bfr0 double-buffered by tile parity: P4 loads
//         next tile's g0 into the other set while this one feeds MFMA P4)
// Restage safety re-derived: every region's reads drain at a counted wait >=1
// barrier before its restage issue (A: drains P1/P3, restaged next-tile P1/P2;
// B: drains P1/P2, restaged P3/P4). P4's cross-buffer reads covered by
// vmcnt(3)+BAR (queue walked: A(n+1),B(n+1) landed; only B(n+2) in flight).
// Geometry/staging/swizzle/vmcnt cadence unchanged from v3 (grid 256 = fill).

#define G1_K  2048
#define G1_NT 32

__global__ __launch_bounds__(512, 2) void k_gemm1_256(
    const ushort_t* __restrict__ A, const ushort_t* __restrict__ Bt,
    ushort_t* __restrict__ C, const float* __restrict__ bias,
    const float* __restrict__ fc, const float* __restrict__ fs,
    ushort_t* __restrict__ Vt) {
    __shared__ __align__(16) ushort_t As[2][16384];   // 2 bufs x 256 rows x 64
    __shared__ __align__(16) ushort_t Bs[2][12288];   // 2 bufs x 192 rows x 64
    int t = threadIdx.x;
    int w = t >> 6, lane = t & 63, quad = lane >> 4, l16 = lane & 15;
    int wm_i = w >> 2, wn_i = w & 3;

    int L = blockIdx.x;                    // 16 mt x 16 nt, m striped per XCD
    int xcd = L & 7, j = L >> 3;           // mper = 16/8 = 2
    int m0 = (xcd * 2 + (j & 1)) * 256;
    int n0 = (j >> 1) * 192;

    int srow = w * 16 + (lane >> 3);
    int sg   = (lane & 7) ^ (lane >> 3);
    const ushort_t* Ag  = A  + (size_t)(m0 + srow) * G1_K + sg * 8;
    const ushort_t* Bg3 = Bt + (size_t)(n0 + w * 8 + (lane >> 3)) * G1_K + sg * 8;

    int swz = l16 & 7;
    int cA = (quad ^ swz) * 8;             // kc=0 chunk (elem offset in row)
    int cB = ((quad + 4) ^ swz) * 8;       // kc=1

    f32x4 acc[8][3] = {};
    bf16x8 afr0[4][2], afr1[4][2];         // A frags for M-half 0 / 1
    bf16x8 b0a[2], b0b[2];                 // g0 frags, double-buffered by tile
    bf16x8 b1[2], b2[2];                   // g1, g2 frags

#define ST1A(KT, HA, BUF) do {                                                  \
    const ushort_t* s_ = Ag + (size_t)(HA) * 128 * G1_K + (KT) * 64;            \
    char* d_ = (char*)&As[BUF][(HA) * 8192] + w * 2048;                         \
    g2l16(s_, d_); g2l16(s_ + 8 * G1_K, d_ + 1024); } while (0)
#define ST1B(KT, G, BUF) do {                                                   \
    const ushort_t* s_ = Bg3 + (size_t)(G) * 64 * G1_K + (KT) * 64;             \
    char* d_ = (char*)&Bs[BUF][(G) * 4096] + w * 1024;                          \
    g2l16(s_, d_); } while (0)

// read A M-half into DST[4][2]  (8 ds_read_b128)
#define RDA_TO(DST, MH, BUF) do {                                               \
    const ushort_t* Ar = &As[BUF][(wm_i * 128 + (MH) * 64 + l16) * 64];         \
    _Pragma("unroll") for (int ii = 0; ii < 4; ii++) {                          \
        DST[ii][0] = *(const bf16x8*)(Ar + ii * 1024 + cA);                     \
        DST[ii][1] = *(const bf16x8*)(Ar + ii * 1024 + cB); } } while (0)
// read B col-group G into DST[2]  (2 ds_read_b128)
#define RDB_TO(DST, G, BUF) do {                                                \
    const ushort_t* Br = &Bs[BUF][(wn_i * 48 + (G) * 16 + l16) * 64];           \
    DST[0] = *(const bf16x8*)(Br + cA);                                         \
    DST[1] = *(const bf16x8*)(Br + cB); } while (0)

// 8 MFMA: acc[MH*4+ii][G] += AFR[ii][kc] * BF[kc]
#define MMA1(AFR, MH, BF, G) do {                                               \
    _Pragma("unroll") for (int kc = 0; kc < 2; kc++)                            \
    _Pragma("unroll") for (int ii = 0; ii < 4; ii++)                            \
        acc[(MH)*4+ii][G] = __builtin_amdgcn_mfma_f32_16x16x32_bf16(            \
            AFR[ii][kc], BF[kc], acc[(MH)*4+ii][G], 0, 0, 0); } while (0)

#define BAR1() __builtin_amdgcn_s_barrier()
#define LGKM(N) do { asm volatile("s_waitcnt lgkmcnt(" #N ")" ::: "memory");    \
                     __builtin_amdgcn_sched_barrier(0); } while (0)

// B0C = bfr0 set consumed this tile; B0N = set loaded at P4 for next tile
#define TILE1(KT, BUF, OTH, B0C, B0N) do {                                      \
    /* P1: stage next-A half0; read g1,g2; MFMA (M0,g0) */                      \
    if ((KT) + 1 < G1_NT) ST1A((KT) + 1, 0, OTH);                               \
    BAR1();                                                                     \
    RDB_TO(b1, 1, BUF); RDB_TO(b2, 2, BUF);                                     \
    LGKM(4);                                                                    \
    __builtin_amdgcn_s_setprio(1); MMA1(afr0, 0, B0C, 0);                       \
    __builtin_amdgcn_s_setprio(0);                                              \
    /* P2: stage next-A half1; read M1; MFMA (M0,g1)+(M0,g2) */                 \
    if ((KT) + 1 < G1_NT) ST1A((KT) + 1, 1, OTH);                               \
    BAR1();                                                                     \
    RDA_TO(afr1, 1, BUF);                                                       \
    LGKM(8);                                                                    \
    __builtin_amdgcn_s_setprio(1); MMA1(afr0, 0, b1, 1); MMA1(afr0, 0, b2, 2);  \
    __builtin_amdgcn_s_setprio(0);                                              \
    /* P3: restage B g0,g1 (drained P1/P2); MFMA (M1,g2)+(M1,g1) */             \
    if ((KT) + 2 < G1_NT) { ST1B((KT) + 2, 0, BUF); ST1B((KT) + 2, 1, BUF); }   \
    BAR1();                                                                     \
    LGKM(0);                                                                    \
    __builtin_amdgcn_s_setprio(1); MMA1(afr1, 1, b2, 2); MMA1(afr1, 1, b1, 1);  \
    __builtin_amdgcn_s_setprio(0);                                              \
    /* P4: restage B g2; counted vmcnt; read NEXT tile's M0+g0; MFMA (M1,g0) */ \
    if ((KT) + 2 < G1_NT) ST1B((KT) + 2, 2, BUF);                               \
    if ((KT) < G1_NT - 2) asm volatile("s_waitcnt vmcnt(3)" ::: "memory");      \
    else                  asm volatile("s_waitcnt vmcnt(0)" ::: "memory");      \
    BAR1();                                                                     \
    if ((KT) + 1 < G1_NT) { RDA_TO(afr0, 0, OTH); RDB_TO(B0N, 0, OTH); }        \
    __builtin_amdgcn_s_setprio(1); MMA1(afr1, 1, B0C, 0);                       \
    __builtin_amdgcn_s_setprio(0);                                              \
} while (0)

    // prologue: t0.{B,A} -> buf0, t1.B -> buf1 (10 loads/thread);
    // vmcnt(3): t0 fully landed, t1's B thirds in flight. Then pre-read
    // tile0's M0 + g0 fragments (drained by tile0-P1's lgkm(4)).
    ST1B(0, 0, 0); ST1B(0, 1, 0); ST1B(0, 2, 0);
    ST1A(0, 0, 0); ST1A(0, 1, 0);
    ST1B(1, 0, 1); ST1B(1, 1, 1); ST1B(1, 2, 1);
    asm volatile("s_waitcnt vmcnt(3)" ::: "memory");
    BAR1();
    RDA_TO(afr0, 0, 0); RDB_TO(b0a, 0, 0);

    for (int kt = 0; kt < G1_NT; kt += 2) {
        TILE1(kt, 0, 1, b0a, b0b);
        TILE1(kt + 1, 1, 0, b0b, b0a);
    }
#undef ST1A
#undef ST1B
#undef RDA_TO
#undef RDB_TO
#undef MMA1
#undef BAR1
#undef LGKM
#undef TILE1

    // epilogue: frag (i,j2) -> r = m0+wm_i*128+i*16+quad*4, c = n0+wn_i*48+j2*16+l16
#pragma unroll
    for (int i = 0; i < 8; i++) {
        int r = m0 + wm_i * 128 + i * 16 + quad * 4;
#pragma unroll
        for (int j2 = 0; j2 < 3; j2++) {
            int c = n0 + wn_i * 48 + j2 * 16 + l16;
            float bv_ = bias[c];
            if (c >= 2560) {                          // V cols -> transposed Vt
                ushort4 pack;
                pack.x = f2bf(acc[i][j2][0] + bv_);
                pack.y = f2bf(acc[i][j2][1] + bv_);
                pack.z = f2bf(acc[i][j2][2] + bv_);
                pack.w = f2bf(acc[i][j2][3] + bv_);
                int kv = (c - 2560) >> 7, d = (c - 2560) & 127;
                int b = r >> 11, s0 = r & (S_ - 1);
                *(ushort4*)&Vt[(((size_t)b * KV_ + kv) * HD_ + d) * S_ + s0] = pack;
                continue;
            }
#pragma unroll
            for (int jr = 0; jr < 4; jr++) {
                float v = acc[i][j2][jr] + bv_;
                int s  = (r + jr) & (S_ - 1);
                int dp = (c & 127) >> 1;
                float cs = fc[s * 64 + dp], sn = fs[s * 64 + dp];
                float p = __shfl_xor(v, 1);           // pair element (c^1)
                v = (c & 1) ? (v * cs + p * sn) : (v * cs - p * sn);
                if (c < 2048) v *= SOFTSC;            // fold softmax scale into Q
                C[(size_t)(r + jr) * NQK + c] = f2bf(v);
            }
        }
    }
}

// ---------------- Flash attention v6: P-LDS swizzle + lean softmax ----------
// (r6: P XOR-swizzle fixed 3.78M bank-conflict cycles; SOFTSC folded into Q;
// native bf16 cast in P-write. Verified passing, dropped out of top-5.)

__global__ __launch_bounds__(512, 4) void k_flash(const ushort_t* __restrict__ QK,
                                                  const ushort_t* __restrict__ Vt,
                                                  ushort_t* __restrict__ AO) {
    __shared__ __align__(16) ushort_t Ks[2 * 8192];
    __shared__ __align__(16) ushort_t Vs[2 * 8192];
    __shared__ __align__(16) ushort_t Ps[8 * 16 * 64];
    int h = blockIdx.y, b = blockIdx.z;
    int qt = b ? ((int)gridDim.x - 1 - (int)blockIdx.x) : (int)blockIdx.x;
    int kvh = h >> 2;
    int t = threadIdx.x, w = t >> 6, lane = t & 63, quad = lane >> 4, l16 = lane & 15;
    int qrow0 = qt * 128 + w * 16;

    bf16x8 aq[4];
    {
        const ushort_t* qb = QK + (size_t)(b * S_ + qrow0 + l16) * NQK + h * HD_ + quad * 8;
#pragma unroll
        for (int kc = 0; kc < 4; kc++) aq[kc] = *(const bf16x8*)(qb + kc * 32);
    }
    bf16x8 vone;
#pragma unroll
    for (int i = 0; i < 8; i++) vone[i] = (__bf16)1.0f;

    f32x4 o[8] = {};
    f32x4 ol = {};                 // row-sum accumulator (softmax denominator)
    ushort_t* Psw = Ps + w * 16 * 64;
    int gsw = (l16 >> 1) & 3;      // K/V read-side swizzle bits

    const ushort_t* kgb = QK + (size_t)(b * S_) * NQK + 2048 + kvh * HD_;
    const ushort_t* vgb = Vt + ((size_t)(b * KV_ + kvh) * HD_) * S_;

    int sr, sgs; char *sK0, *sV0;
    if (t < 256) {
        sr = t >> 2; sgs = (t & 3) ^ ((sr >> 1) & 3);
        sK0 = (char*)Ks + (t >> 6) * 1024;
        sV0 = nullptr;
    } else {
        int u = t - 256;
        sr = u >> 2; sgs = (u & 3) ^ ((sr >> 1) & 3);
        sV0 = (char*)Vs + ((t - 256) >> 6) * 1024;
        sK0 = nullptr;
    }

#define STAGE(KT, BUF)                                                          \
    do {                                                                        \
        if (t < 256) {                                                          \
            const ushort_t* kg = kgb + (size_t)((KT) * 64 + sr) * NQK + sgs * 8; \
            char* KsW = sK0 + (BUF) * 16384;                                    \
            _Pragma("unroll")                                                   \
            for (int p = 0; p < 4; p++) g2l16(kg + p * 32, KsW + p * 4096);     \
        } else {                                                                \
            const ushort_t* vg = vgb + (KT) * 64 + sgs * 8 + (size_t)sr * S_;   \
            char* VsW = sV0 + (BUF) * 16384;                                    \
            _Pragma("unroll")                                                   \
            for (int p = 0; p < 4; p++)                                         \
                g2l16(vg + (size_t)((p & 1) * 64) * S_ + (p >> 1) * 32, VsW + p * 4096); \
        }                                                                       \
    } while (0)

    int ktmax = 2 * qt + 1;
    STAGE(0, 0);
    __syncthreads();

    for (int kt = 0; kt <= ktmax; kt++) {
        int cur = kt & 1;
        if (kt < ktmax) STAGE(kt + 1, cur ^ 1);   // prefetch next tile

        if (kt * 64 <= qrow0 + 15) {              // else fully-masked for this wave
            const ushort_t* Kc = Ks + cur * 8192;
            const ushort_t* Vc = Vs + cur * 8192;
            f32x4 sacc[4] = {};
            __builtin_amdgcn_s_setprio(1);        // T5: favor MFMA wave (m191)
#pragma unroll
            for (int kc = 0; kc < 4; kc++)
#pragma unroll
                for (int nb = 0; nb < 4; nb++) {
                    bf16x8 bk = *(const bf16x8*)(Kc + kc * 2048 + (nb * 16 + l16) * 32 + ((quad ^ gsw) * 8));
                    sacc[nb] = __builtin_amdgcn_mfma_f32_16x16x32_bf16(aq[kc], bk, sacc[nb], 0, 0, 0);
                }
            __builtin_amdgcn_s_setprio(0);
            if (kt * 64 + 63 > qrow0) {           // diagonal tile: causal mask
#pragma unroll
                for (int nb = 0; nb < 4; nb++)
#pragma unroll
                    for (int jr = 0; jr < 4; jr++) {
                        int kcol = kt * 64 + nb * 16 + l16;
                        int qr = qrow0 + quad * 4 + jr;
                        if (kcol > qr) sacc[nb][jr] = -1e30f;
                    }
            }
            // P write, granule-swizzled: slot (key>>3)^(q&7) of row q
#pragma unroll
            for (int nb = 0; nb < 4; nb++)
#pragma unroll
                for (int jr = 0; jr < 4; jr++) {
                    int q  = quad * 4 + jr;
                    int gi = (nb * 2 + (l16 >> 3)) ^ (q & 7);
                    Psw[q * 64 + gi * 8 + (l16 & 7)] = f2bf_fast(exp2f(sacc[nb][jr]));
                }

            asm volatile("s_waitcnt lgkmcnt(0)" ::: "memory");  // P writes -> A-frag reads

            __builtin_amdgcn_s_setprio(1);        // T5: favor MFMA wave (m191)
#pragma unroll
            for (int kc2 = 0; kc2 < 2; kc2++) {
                bf16x8 ap = *(const bf16x8*)(Psw + l16 * 64 + (((kc2 * 4 + quad) ^ (l16 & 7)) * 8));
                ol = __builtin_amdgcn_mfma_f32_16x16x32_bf16(ap, vone, ol, 0, 0, 0);
#pragma unroll
                for (int db = 0; db < 8; db++) {
                    bf16x8 bv = *(const bf16x8*)(Vc + kc2 * 4096 + (db * 16 + l16) * 32 + ((quad ^ gsw) * 8));
                    o[db] = __builtin_amdgcn_mfma_f32_16x16x32_bf16(ap, bv, o[db], 0, 0, 0);
                }
            }
            __builtin_amdgcn_s_setprio(0);
        }
        __syncthreads();   // next tile staged + this tile's LDS reads done
    }
#undef STAGE

    // epilogue: divide by l, write bf16
#pragma unroll
    for (int jr = 0; jr < 4; jr++) {
        float inv = 1.0f / ol[jr];
        size_t rbase = (size_t)(b * S_ + qrow0 + quad * 4 + jr) * D_ + h * HD_;
#pragma unroll
        for (int db = 0; db < 8; db++)
            AO[rbase + db * 16 + l16] = f2bf(o[db][jr] * inv);
    }
}

// ---------------- launch ----------------

extern "C" void kernel_launch(void* const* d_in, const int* in_sizes, int n_in,
                              void* d_out, int out_size, void* d_ws, size_t ws_size,
                              hipStream_t stream) {
    const float* x  = (const float*)d_in[0];
    // d_in[1] = mask (all zeros; reference ignores it — causal built in-kernel)
    const float* fc = (const float*)d_in[2];
    const float* fs = (const float*)d_in[3];
    const float* Wq = (const float*)d_in[4];
    const float* bq = (const float*)d_in[5];
    const float* Wk = (const float*)d_in[6];
    const float* bk = (const float*)d_in[7];
    const float* Wv = (const float*)d_in[8];
    const float* bv = (const float*)d_in[9];
    const float* Wo = (const float*)d_in[10];

    char* ws = (char*)d_ws;
    // layout (bytes); AO aliases xb (xb dead after gemm1). Vt is its own 4 MB
    // (must NOT alias Wt: gemm1 reads Wt while writing Vt). QK stride 2560.
    ushort_t* xb  = (ushort_t*)(ws);                 // 16 MB  (4096x2048 bf16)
    ushort_t* Wt  = (ushort_t*)(ws + 16777216);      // 12 MB  (3072x2048 bf16)
    ushort_t* Wot = (ushort_t*)(ws + 29360128);      //  8 MB  (2048x2048 bf16)
    float*    bb  = (float*)   (ws + 37748736);      // 12 KB
    ushort_t* QK  = (ushort_t*)(ws + 37761024);      // 20 MB  (4096x2560 bf16)
    ushort_t* Vt  = (ushort_t*)(ws + 58732544);      //  4 MB  (2*4*128*2048 bf16)
    ushort_t* AO  = xb;                              // 16 MB  (4096x2048 bf16)
    float* out = (float*)d_out;

    k_prep<<<18444, 256, 0, stream>>>(x, xb, Wq, Wk, Wv, Wo, Wt, Wot, bq, bk, bv, bb);
    k_gemm1_256<<<256, 512, 0, stream>>>(xb, Wt, QK, bb, fc, fs, Vt);
    k_flash<<<dim3(16, 16, 2), 512, 0, stream>>>(QK, Vt, AO);
    k_gemm<128><<<512, 256, 0, stream>>>(AO, Wot, out, nullptr, nullptr, nullptr, nullptr,
                                         4096, 2048, 2048, 0);
}

// Round 8
// 302.616 us; speedup vs baseline: 1.0714x; 1.0032x over previous
//
#include <hip/hip_runtime.h>

// Fused GQA attention block: QKV proj(+RoPE, +V-transpose) -> flash attn -> out proj.
// B=2 S=2048 D=2048 H=16 KV=4 HD=128. All MFMA compute in bf16 (tol = 2% of max).

#define B_  2
#define S_  2048
#define D_  2048
#define H_  16
#define KV_ 4
#define HD_ 128
#define NQK 2560    // QK buffer row stride: 2048 (Q) + 512 (K); V goes to Vt directly

typedef unsigned short ushort_t;
typedef __attribute__((ext_vector_type(8))) __bf16 bf16x8;
typedef __attribute__((ext_vector_type(4))) float  f32x4;

__device__ __forceinline__ ushort_t f2bf(float f) {
    unsigned u = __float_as_uint(f);
    u += 0x7FFFu + ((u >> 16) & 1u);          // round-to-nearest-even
    return (ushort_t)(u >> 16);
}
// compiler-native cast (emits v_cvt_pk_bf16_f32, RNE) — 1 op vs 4 for f2bf
__device__ __forceinline__ ushort_t f2bf_fast(float f) {
    __bf16 h = (__bf16)f;
    return *(ushort_t*)&h;
}
__device__ __forceinline__ float bf2f(ushort_t h) {
    return __uint_as_float(((unsigned)h) << 16);
}

// async global->LDS, 16B per lane; LDS dest = wave-uniform base + lane*16
__device__ __forceinline__ void g2l16(const void* g, void* l) {
    __builtin_amdgcn_global_load_lds(
        (const __attribute__((address_space(1))) unsigned int*)g,
        (__attribute__((address_space(3))) unsigned int*)l, 16, 0, 0);
}

// softmax scale 1/sqrt(128)*log2(e), folded into gemm1's Q epilogue (r6)
#define SOFTSC 0.12751743f

// ---------------- fused prep: x->bf16, 4 weight transposes, bias pack -------

__global__ __launch_bounds__(256) void k_prep(
    const float* __restrict__ x,  ushort_t* __restrict__ xb,
    const float* __restrict__ Wq, const float* __restrict__ Wk,
    const float* __restrict__ Wv, const float* __restrict__ Wo,
    ushort_t* __restrict__ Wt, ushort_t* __restrict__ Wot,
    const float* __restrict__ bq, const float* __restrict__ bk,
    const float* __restrict__ bv, float* __restrict__ bb) {
    __shared__ float tile[32][33];
    int id = blockIdx.x, t = threadIdx.x;
    if (id < 8192) {                                   // x fp32 -> bf16
        int i = id * 256 + t;
        float4 v = ((const float4*)x)[i];
        ushort4 o;
        o.x = f2bf(v.x); o.y = f2bf(v.y); o.z = f2bf(v.z); o.w = f2bf(v.w);
        ((ushort4*)xb)[i] = o;
        return;
    }
    const float* src; ushort_t* dst; int C, bid;
    if (id < 12288)      { src = Wq; dst = Wt;                       C = 2048; bid = id - 8192;  }
    else if (id < 13312) { src = Wk; dst = Wt + (size_t)2048 * 2048; C = 512;  bid = id - 12288; }
    else if (id < 14336) { src = Wv; dst = Wt + (size_t)2560 * 2048; C = 512;  bid = id - 13312; }
    else if (id < 18432) { src = Wo; dst = Wot;                      C = 2048; bid = id - 14336; }
    else {                                             // bias pack
        int i = (id - 18432) * 256 + t;
        if (i < 3072)
            bb[i] = (i < 2048) ? bq[i] : (i < 2560) ? bk[i - 2048] : bv[i - 2560];
        return;
    }
    const int R = 2048;
    int nbc = C >> 5;
    int c0 = (bid % nbc) * 32, r0 = (bid / nbc) * 32;
    int tx = t & 31, ty = t >> 5;
    for (int i = ty; i < 32; i += 8)
        tile[i][tx] = src[(size_t)(r0 + i) * C + c0 + tx];
    __syncthreads();
    for (int i = ty; i < 32; i += 8)
        dst[(size_t)(c0 + i) * R + r0 + tx] = f2bf(tile[tx][i]);
}

// ---------------- gemm2: 128x128 tile, 2-phase (unchanged, out proj only) ---

template<int BK>
__global__ __launch_bounds__(256, 3) void k_gemm(const ushort_t* __restrict__ A,
                                                 const ushort_t* __restrict__ Bt,
                                                 void* __restrict__ Cp,
                                                 const float* __restrict__ bias,
                                                 const float* __restrict__ fc,
                                                 const float* __restrict__ fs,
                                                 ushort_t* __restrict__ Vt,
                                                 int M, int N, int K, int out_bf16) {
    constexpr int GPR    = BK / 8;    // 16B granules per row
    constexpr int RPR    = 64 / GPR;  // rows staged per round per wave
    constexpr int ROUNDS = 32 / RPR;  // rounds to cover 32 rows per wave
    __shared__ __align__(16) ushort_t As[128 * BK];
    __shared__ __align__(16) ushort_t Bs[128 * BK];
    int t = threadIdx.x;
    int w = t >> 6, lane = t & 63, quad = lane >> 4, l16 = lane & 15;
    int L = blockIdx.x;
    int mper = (M >> 7) >> 3;                 // m-tiles per XCD
    int xcd = L & 7, j = L >> 3;
    int m0 = (xcd * mper + (j % mper)) * 128;
    int n0 = (j / mper) * 128;
    int wm = (w >> 1) * 64, wn = (w & 1) * 64;
    f32x4 acc[4][4] = {};

    int rlo = lane / GPR;                     // row-within-round
    int gsl = lane & (GPR - 1);               // slot granule
    const ushort_t* Ag = A  + (size_t)(m0 + w * 32) * K;
    const ushort_t* Bg = Bt + (size_t)(n0 + w * 32) * K;
    int rsw = (l16 & 7);                      // read-side swizzle bits

    for (int k0 = 0; k0 < K; k0 += BK) {
        __syncthreads();
#pragma unroll
        for (int p = 0; p < ROUNDS; p++) {
            int row = p * RPR + rlo;
            int gs = gsl ^ (row & 7);
            g2l16(Ag + (size_t)row * K + k0 + gs * 8, (char*)As + (w * 32 + p * RPR) * 2 * BK);
            g2l16(Bg + (size_t)row * K + k0 + gs * 8, (char*)Bs + (w * 32 + p * RPR) * 2 * BK);
        }
        __syncthreads();
#pragma unroll
        for (int kc = 0; kc < BK / 32; kc++) {
            int gg = quad + kc * 4;
            bf16x8 af[4], bfr[4];
#pragma unroll
            for (int i = 0; i < 4; i++)
                af[i] = *(const bf16x8*)(As + (wm + i * 16 + l16) * BK + ((gg ^ rsw) * 8));
#pragma unroll
            for (int j2 = 0; j2 < 4; j2++)
                bfr[j2] = *(const bf16x8*)(Bs + (wn + j2 * 16 + l16) * BK + ((gg ^ rsw) * 8));
#pragma unroll
            for (int i = 0; i < 4; i++)
#pragma unroll
                for (int j2 = 0; j2 < 4; j2++)
                    acc[i][j2] = __builtin_amdgcn_mfma_f32_16x16x32_bf16(af[i], bfr[j2], acc[i][j2], 0, 0, 0);
        }
    }
    int ostride = fc ? NQK : N;
#pragma unroll
    for (int i = 0; i < 4; i++) {
        int r = m0 + wm + i * 16 + quad * 4;
#pragma unroll
        for (int j2 = 0; j2 < 4; j2++) {
            int c = n0 + wn + j2 * 16 + l16;
            float bv_ = bias ? bias[c] : 0.f;
            if (fc && c >= 2560) {
                ushort4 pack;
                pack.x = f2bf(acc[i][j2][0] + bv_);
                pack.y = f2bf(acc[i][j2][1] + bv_);
                pack.z = f2bf(acc[i][j2][2] + bv_);
                pack.w = f2bf(acc[i][j2][3] + bv_);
                int kv = (c - 2560) >> 7, d = (c - 2560) & 127;
                int b = r >> 11, s0 = r & (S_ - 1);
                *(ushort4*)&Vt[(((size_t)b * KV_ + kv) * HD_ + d) * S_ + s0] = pack;
                continue;
            }
#pragma unroll
            for (int jr = 0; jr < 4; jr++) {
                float v = acc[i][j2][jr] + bv_;
                if (fc) {
                    int s  = (r + jr) & (S_ - 1);
                    int dp = (c & 127) >> 1;
                    float cs = fc[s * 64 + dp], sn = fs[s * 64 + dp];
                    float p = __shfl_xor(v, 1);
                    v = (c & 1) ? (v * cs + p * sn) : (v * cs - p * sn);
                }
                if (out_bf16) ((ushort_t*)Cp)[(size_t)(r + jr) * ostride + c] = f2bf(v);
                else          ((float*)Cp)[(size_t)(r + jr) * ostride + c] = v;
            }
        }
    }
}

// ---------------- gemm1: 128x192 tile, 2 blocks/CU, v5 ----------------------
// r8 post-mortem of v4 (67us, neutral vs v3): the binding constraint was
// OCCUPANCY, not schedule. 112KB LDS -> 1 block/CU -> 8 waves with nothing to
// overlap barriers/waits. v5: tile 128x192, LDS = 2x16K (A) + 2x24K (B) =
// exactly 80KB -> 2 blocks/CU (like k_flash), 16 waves/CU. Grid 32mt x 16nt
// = 512 blocks (2x fill, 512%8==0 bijective XCD swizzle). Per-wave 64x48 out
// = acc[4][3] (~120 VGPR total, fits (512,4) 128 cap).
// Both operands strictly double-buffered -> only 2 barriers/tile:
//   P1: st A0,B0(n+1)->oth; rd afr(all)+g0; lgkm0; MFMA g0
//   P2: st A1,B1(n+1)->oth; rd g1;          lgkm0; MFMA g1
//   P3: st B2(n+1)->oth; vmcnt(1); BAR[vis]; rd g2; lgkm0; MFMA g2; BAR[tile]
// vmcnt queue (walked, steady state): entering tile n outstanding = B2(n);
// P3's vmcnt(1) drains B2(n) + A0,B0,A1,B1(n+1), leaves B2(n+1) -> next
// tile's P1/P2 reads are covered; B2(n) read sits after this tile's
// vmcnt+BAR. Restage-vs-read: all writes go to oth; a region of oth was last
// read in tile n-1, whose reads are drained by each wave's lgkm(0) before
// the tile-boundary BAR that precedes tile n's first stage. 2-block/CU
// overlap hides the remaining per-phase latency.

#define G1_K  2048
#define G1_NT 32

__global__ __launch_bounds__(512, 4) void k_gemm1_256(
    const ushort_t* __restrict__ A, const ushort_t* __restrict__ Bt,
    ushort_t* __restrict__ C, const float* __restrict__ bias,
    const float* __restrict__ fc, const float* __restrict__ fs,
    ushort_t* __restrict__ Vt) {
    __shared__ __align__(16) ushort_t As[2][8192];    // 2 bufs x 128 rows x 64
    __shared__ __align__(16) ushort_t Bs[2][12288];   // 2 bufs x 192 rows x 64
    int t = threadIdx.x;
    int w = t >> 6, lane = t & 63, quad = lane >> 4, l16 = lane & 15;
    int wm_i = w >> 2, wn_i = w & 3;

    int L = blockIdx.x;                    // 32 mt x 16 nt, m striped per XCD
    int xcd = L & 7, j = L >> 3;           // mper = 32/8 = 4
    int m0 = (xcd * 4 + (j & 3)) * 128;
    int n0 = (j >> 2) * 192;

    // staging: region unit = 64 rows x 64 k = 8KB = 1 g2l16/thread (uniform
    // per-thread load counts -> vmcnt(N) semantics identical for all waves).
    // A = 2 halves, B = 3 thirds. Wave w writes rows w*8..+7 linearly; lane's
    // global source granule pre-swizzled: LDS slot s of row r holds global
    // granule s^(r&7)  (r&7 == lane>>3 since region row = w*8+(lane>>3)).
    int srow = w * 8 + (lane >> 3);
    int sg   = (lane & 7) ^ (lane >> 3);
    const ushort_t* Ag  = A  + (size_t)(m0 + srow) * G1_K + sg * 8;
    const ushort_t* Bg3 = Bt + (size_t)(n0 + srow) * G1_K + sg * 8;

    int swz = l16 & 7;
    int cA = (quad ^ swz) * 8;             // kc=0 chunk (elem offset in row)
    int cB = ((quad + 4) ^ swz) * 8;       // kc=1

    f32x4 acc[4][3] = {};
    bf16x8 afr[4][2], bf_[2];

#define ST_A(KT, HA, BUF) do {                                                  \
    const ushort_t* s_ = Ag + (size_t)(HA) * 64 * G1_K + (KT) * 64;             \
    char* d_ = (char*)&As[BUF][(HA) * 4096] + w * 1024;                         \
    g2l16(s_, d_); } while (0)
#define ST_B(KT, G, BUF) do {                                                   \
    const ushort_t* s_ = Bg3 + (size_t)(G) * 64 * G1_K + (KT) * 64;             \
    char* d_ = (char*)&Bs[BUF][(G) * 4096] + w * 1024;                          \
    g2l16(s_, d_); } while (0)

// read this wave's full A panel (4 ii x 2 kc = 8 ds_read_b128)
#define RDA(BUF) do {                                                           \
    const ushort_t* Ar = &As[BUF][(wm_i * 64 + l16) * 64];                      \
    _Pragma("unroll") for (int ii = 0; ii < 4; ii++) {                          \
        afr[ii][0] = *(const bf16x8*)(Ar + ii * 1024 + cA);                     \
        afr[ii][1] = *(const bf16x8*)(Ar + ii * 1024 + cB); } } while (0)
// read B col-group G (2 ds_read_b128)
#define RDB(G, BUF) do {                                                        \
    const ushort_t* Br = &Bs[BUF][(wn_i * 48 + (G) * 16 + l16) * 64];           \
    bf_[0] = *(const bf16x8*)(Br + cA);                                         \
    bf_[1] = *(const bf16x8*)(Br + cB); } while (0)

#define MMA(G) do {                                                             \
    _Pragma("unroll") for (int kc = 0; kc < 2; kc++)                            \
    _Pragma("unroll") for (int ii = 0; ii < 4; ii++)                            \
        acc[ii][G] = __builtin_amdgcn_mfma_f32_16x16x32_bf16(                   \
            afr[ii][kc], bf_[kc], acc[ii][G], 0, 0, 0); } while (0)

#define BAR1() __builtin_amdgcn_s_barrier()
#define LGKM0() do { asm volatile("s_waitcnt lgkmcnt(0)" ::: "memory");         \
                     __builtin_amdgcn_sched_barrier(0); } while (0)

#define TILE(KT, BUF, OTH) do {                                                 \
    /* P1 */                                                                    \
    if ((KT) + 1 < G1_NT) { ST_A((KT) + 1, 0, OTH); ST_B((KT) + 1, 0, OTH); }   \
    RDA(BUF); RDB(0, BUF);                                                      \
    LGKM0();                                                                    \
    __builtin_amdgcn_s_setprio(1); MMA(0); __builtin_amdgcn_s_setprio(0);       \
    /* P2 */                                                                    \
    if ((KT) + 1 < G1_NT) { ST_A((KT) + 1, 1, OTH); ST_B((KT) + 1, 1, OTH); }   \
    RDB(1, BUF);                                                                \
    LGKM0();                                                                    \
    __builtin_amdgcn_s_setprio(1); MMA(1); __builtin_amdgcn_s_setprio(0);       \
    /* P3 */                                                                    \
    if ((KT) + 1 < G1_NT) ST_B((KT) + 1, 2, OTH);                               \
    if ((KT) + 1 < G1_NT) asm volatile("s_waitcnt vmcnt(1)" ::: "memory");      \
    else                  asm volatile("s_waitcnt vmcnt(0)" ::: "memory");      \
    BAR1();                                                                     \
    RDB(2, BUF);                                                                \
    LGKM0();                                                                    \
    __builtin_amdgcn_s_setprio(1); MMA(2); __builtin_amdgcn_s_setprio(0);       \
    BAR1();                                                                     \
} while (0)

    // prologue: tile0 {A0,A1,B0,B1,B2} -> buf0 (5 loads/thread), full drain.
    ST_A(0, 0, 0); ST_A(0, 1, 0);
    ST_B(0, 0, 0); ST_B(0, 1, 0); ST_B(0, 2, 0);
    asm volatile("s_waitcnt vmcnt(0)" ::: "memory");
    BAR1();

    for (int kt = 0; kt < G1_NT; kt += 2) {
        TILE(kt, 0, 1);
        TILE(kt + 1, 1, 0);
    }
#undef ST_A
#undef ST_B
#undef RDA
#undef RDB
#undef MMA
#undef BAR1
#undef LGKM0
#undef TILE

    // epilogue: frag (i,j2) -> r = m0+wm_i*64+i*16+quad*4, c = n0+wn_i*48+j2*16+l16
#pragma unroll
    for (int i = 0; i < 4; i++) {
        int r = m0 + wm_i * 64 + i * 16 + quad * 4;
#pragma unroll
        for (int j2 = 0; j2 < 3; j2++) {
            int c = n0 + wn_i * 48 + j2 * 16 + l16;
            float bv_ = bias[c];
            if (c >= 2560) {                          // V cols -> transposed Vt
                ushort4 pack;
                pack.x = f2bf(acc[i][j2][0] + bv_);
                pack.y = f2bf(acc[i][j2][1] + bv_);
                pack.z = f2bf(acc[i][j2][2] + bv_);
                pack.w = f2bf(acc[i][j2][3] + bv_);
                int kv = (c - 2560) >> 7, d = (c - 2560) & 127;
                int b = r >> 11, s0 = r & (S_ - 1);
                *(ushort4*)&Vt[(((size_t)b * KV_ + kv) * HD_ + d) * S_ + s0] = pack;
                continue;
            }
#pragma unroll
            for (int jr = 0; jr < 4; jr++) {
                float v = acc[i][j2][jr] + bv_;
                int s  = (r + jr) & (S_ - 1);
                int dp = (c & 127) >> 1;
                float cs = fc[s * 64 + dp], sn = fs[s * 64 + dp];
                float p = __shfl_xor(v, 1);           // pair element (c^1)
                v = (c & 1) ? (v * cs + p * sn) : (v * cs - p * sn);
                if (c < 2048) v *= SOFTSC;            // fold softmax scale into Q
                C[(size_t)(r + jr) * NQK + c] = f2bf(v);
            }
        }
    }
}

// ---------------- Flash attention v6: P-LDS swizzle + lean softmax ----------
// (r6: P XOR-swizzle fixed 3.78M bank-conflict cycles; SOFTSC folded into Q;
// native bf16 cast in P-write. Verified passing, dropped out of top-5.)

__global__ __launch_bounds__(512, 4) void k_flash(const ushort_t* __restrict__ QK,
                                                  const ushort_t* __restrict__ Vt,
                                                  ushort_t* __restrict__ AO) {
    __shared__ __align__(16) ushort_t Ks[2 * 8192];
    __shared__ __align__(16) ushort_t Vs[2 * 8192];
    __shared__ __align__(16) ushort_t Ps[8 * 16 * 64];
    int h = blockIdx.y, b = blockIdx.z;
    int qt = b ? ((int)gridDim.x - 1 - (int)blockIdx.x) : (int)blockIdx.x;
    int kvh = h >> 2;
    int t = threadIdx.x, w = t >> 6, lane = t & 63, quad = lane >> 4, l16 = lane & 15;
    int qrow0 = qt * 128 + w * 16;

    bf16x8 aq[4];
    {
        const ushort_t* qb = QK + (size_t)(b * S_ + qrow0 + l16) * NQK + h * HD_ + quad * 8;
#pragma unroll
        for (int kc = 0; kc < 4; kc++) aq[kc] = *(const bf16x8*)(qb + kc * 32);
    }
    bf16x8 vone;
#pragma unroll
    for (int i = 0; i < 8; i++) vone[i] = (__bf16)1.0f;

    f32x4 o[8] = {};
    f32x4 ol = {};                 // row-sum accumulator (softmax denominator)
    ushort_t* Psw = Ps + w * 16 * 64;
    int gsw = (l16 >> 1) & 3;      // K/V read-side swizzle bits

    const ushort_t* kgb = QK + (size_t)(b * S_) * NQK + 2048 + kvh * HD_;
    const ushort_t* vgb = Vt + ((size_t)(b * KV_ + kvh) * HD_) * S_;

    int sr, sgs; char *sK0, *sV0;
    if (t < 256) {
        sr = t >> 2; sgs = (t & 3) ^ ((sr >> 1) & 3);
        sK0 = (char*)Ks + (t >> 6) * 1024;
        sV0 = nullptr;
    } else {
        int u = t - 256;
        sr = u >> 2; sgs = (u & 3) ^ ((sr >> 1) & 3);
        sV0 = (char*)Vs + ((t - 256) >> 6) * 1024;
        sK0 = nullptr;
    }

#define STAGE(KT, BUF)                                                          \
    do {                                                                        \
        if (t < 256) {                                                          \
            const ushort_t* kg = kgb + (size_t)((KT) * 64 + sr) * NQK + sgs * 8; \
            char* KsW = sK0 + (BUF) * 16384;                                    \
            _Pragma("unroll")                                                   \
            for (int p = 0; p < 4; p++) g2l16(kg + p * 32, KsW + p * 4096);     \
        } else {                                                                \
            const ushort_t* vg = vgb + (KT) * 64 + sgs * 8 + (size_t)sr * S_;   \
            char* VsW = sV0 + (BUF) * 16384;                                    \
            _Pragma("unroll")                                                   \
            for (int p = 0; p < 4; p++)                                         \
                g2l16(vg + (size_t)((p & 1) * 64) * S_ + (p >> 1) * 32, VsW + p * 4096); \
        }                                                                       \
    } while (0)

    int ktmax = 2 * qt + 1;
    STAGE(0, 0);
    __syncthreads();

    for (int kt = 0; kt <= ktmax; kt++) {
        int cur = kt & 1;
        if (kt < ktmax) STAGE(kt + 1, cur ^ 1);   // prefetch next tile

        if (kt * 64 <= qrow0 + 15) {              // else fully-masked for this wave
            const ushort_t* Kc = Ks + cur * 8192;
            const ushort_t* Vc = Vs + cur * 8192;
            f32x4 sacc[4] = {};
            __builtin_amdgcn_s_setprio(1);        // T5: favor MFMA wave (m191)
#pragma unroll
            for (int kc = 0; kc < 4; kc++)
#pragma unroll
                for (int nb = 0; nb < 4; nb++) {
                    bf16x8 bk = *(const bf16x8*)(Kc + kc * 2048 + (nb * 16 + l16) * 32 + ((quad ^ gsw) * 8));
                    sacc[nb] = __builtin_amdgcn_mfma_f32_16x16x32_bf16(aq[kc], bk, sacc[nb], 0, 0, 0);
                }
            __builtin_amdgcn_s_setprio(0);
            if (kt * 64 + 63 > qrow0) {           // diagonal tile: causal mask
#pragma unroll
                for (int nb = 0; nb < 4; nb++)
#pragma unroll
                    for (int jr = 0; jr < 4; jr++) {
                        int kcol = kt * 64 + nb * 16 + l16;
                        int qr = qrow0 + quad * 4 + jr;
                        if (kcol > qr) sacc[nb][jr] = -1e30f;
                    }
            }
            // P write, granule-swizzled: slot (key>>3)^(q&7) of row q
#pragma unroll
            for (int nb = 0; nb < 4; nb++)
#pragma unroll
                for (int jr = 0; jr < 4; jr++) {
                    int q  = quad * 4 + jr;
                    int gi = (nb * 2 + (l16 >> 3)) ^ (q & 7);
                    Psw[q * 64 + gi * 8 + (l16 & 7)] = f2bf_fast(exp2f(sacc[nb][jr]));
                }

            asm volatile("s_waitcnt lgkmcnt(0)" ::: "memory");  // P writes -> A-frag reads

            __builtin_amdgcn_s_setprio(1);        // T5: favor MFMA wave (m191)
#pragma unroll
            for (int kc2 = 0; kc2 < 2; kc2++) {
                bf16x8 ap = *(const bf16x8*)(Psw + l16 * 64 + (((kc2 * 4 + quad) ^ (l16 & 7)) * 8));
                ol = __builtin_amdgcn_mfma_f32_16x16x32_bf16(ap, vone, ol, 0, 0, 0);
#pragma unroll
                for (int db = 0; db < 8; db++) {
                    bf16x8 bv = *(const bf16x8*)(Vc + kc2 * 4096 + (db * 16 + l16) * 32 + ((quad ^ gsw) * 8));
                    o[db] = __builtin_amdgcn_mfma_f32_16x16x32_bf16(ap, bv, o[db], 0, 0, 0);
                }
            }
            __builtin_amdgcn_s_setprio(0);
        }
        __syncthreads();   // next tile staged + this tile's LDS reads done
    }
#undef STAGE

    // epilogue: divide by l, write bf16
#pragma unroll
    for (int jr = 0; jr < 4; jr++) {
        float inv = 1.0f / ol[jr];
        size_t rbase = (size_t)(b * S_ + qrow0 + quad * 4 + jr) * D_ + h * HD_;
#pragma unroll
        for (int db = 0; db < 8; db++)
            AO[rbase + db * 16 + l16] = f2bf(o[db][jr] * inv);
    }
}

// ---------------- launch ----------------

extern "C" void kernel_launch(void* const* d_in, const int* in_sizes, int n_in,
                              void* d_out, int out_size, void* d_ws, size_t ws_size,
                              hipStream_t stream) {
    const float* x  = (const float*)d_in[0];
    // d_in[1] = mask (all zeros; reference ignores it — causal built in-kernel)
    const float* fc = (const float*)d_in[2];
    const float* fs = (const float*)d_in[3];
    const float* Wq = (const float*)d_in[4];
    const float* bq = (const float*)d_in[5];
    const float* Wk = (const float*)d_in[6];
    const float* bk = (const float*)d_in[7];
    const float* Wv = (const float*)d_in[8];
    const float* bv = (const float*)d_in[9];
    const float* Wo = (const float*)d_in[10];

    char* ws = (char*)d_ws;
    // layout (bytes); AO aliases xb (xb dead after gemm1). Vt is its own 4 MB
    // (must NOT alias Wt: gemm1 reads Wt while writing Vt). QK stride 2560.
    ushort_t* xb  = (ushort_t*)(ws);                 // 16 MB  (4096x2048 bf16)
    ushort_t* Wt  = (ushort_t*)(ws + 16777216);      // 12 MB  (3072x2048 bf16)
    ushort_t* Wot = (ushort_t*)(ws + 29360128);      //  8 MB  (2048x2048 bf16)
    float*    bb  = (float*)   (ws + 37748736);      // 12 KB
    ushort_t* QK  = (ushort_t*)(ws + 37761024);      // 20 MB  (4096x2560 bf16)
    ushort_t* Vt  = (ushort_t*)(ws + 58732544);      //  4 MB  (2*4*128*2048 bf16)
    ushort_t* AO  = xb;                              // 16 MB  (4096x2048 bf16)
    float* out = (float*)d_out;

    k_prep<<<18444, 256, 0, stream>>>(x, xb, Wq, Wk, Wv, Wo, Wt, Wot, bq, bk, bv, bb);
    k_gemm1_256<<<512, 512, 0, stream>>>(xb, Wt, QK, bb, fc, fs, Vt);
    k_flash<<<dim3(16, 16, 2), 512, 0, stream>>>(QK, Vt, AO);
    k_gemm<128><<<512, 256, 0, stream>>>(AO, Wot, out, nullptr, nullptr, nullptr, nullptr,
                                         4096, 2048, 2048, 0);
}